// Round 12
// baseline (676.158 us; speedup 1.0000x reference)
//
#include <hip/hip_runtime.h>

#define TTL 98
#define OUTD 10

typedef float f16v __attribute__((ext_vector_type(16)));
typedef short short8 __attribute__((ext_vector_type(8)));
typedef unsigned long ul2 __attribute__((ext_vector_type(2)));
typedef unsigned short ushort;

constexpr size_t MM = 1048576;
constexpr size_t OFF_OSUM = 5 * MM;                  // 10,240
constexpr size_t OFF_XT   = OFF_OSUM + 10240;        // 802,816 (tables reuse after kL1)
constexpr size_t OFF_S1B  = OFF_XT + 802816;         // u32: 98*512*32
constexpr size_t OFF_S2B  = OFF_S1B + 1605632;       // u32: 98*352*32
constexpr size_t OFF_S1BT = OFF_S2B + 1103872;       // u32: 98*16*1024 (bit-transposed L1)
constexpr size_t OFF_S2BT = OFF_S1BT + 1605632;      // u32: 98*11*1024 (bit-transposed L2)
constexpr size_t OFF_W2S  = OFF_S2BT + 1103872;      // bf16 3*2*1024*512
constexpr size_t OFF_W3S  = OFF_W2S + 1572864;       // bf16 3*3*1024*344
constexpr size_t FIX_END  = OFF_W3S + 1585152;       // 14,632,960 floats (58.5 MB)

constexpr size_t TAB_IDX2 = 0;        // 98*384
constexpr size_t TAB_IDX3 = 37632;    // 98*320
constexpr size_t TAB_CQ3  = 269696;   // 98*352
constexpr size_t TAB_L2   = 304192;   // 1024*33 packed (t<<10|rk), exactly 33 per row
constexpr size_t TAB_L3   = 337984;   // 1024*25 packed, exactly 25 per row

// AW3 per-t footprint: 3 * 320 * 352 ushort = 337,920 ushort = 168,960 floats (FULL size).
constexpr size_t AW3_PER_T = 168960;

// ---- exact 3-way bf16 split by truncation: hi+mid+lo == w bit-exactly ----
__device__ inline void split3(float w, ushort& h, ushort& m, ushort& l) {
    unsigned u = __float_as_uint(w);
    h = (ushort)(u >> 16);
    float r1 = w - __uint_as_float(u & 0xFFFF0000u);
    unsigned u1 = __float_as_uint(r1);
    m = (ushort)(u1 >> 16);
    float r2 = r1 - __uint_as_float(u1 & 0xFFFF0000u);
    l = (ushort)(__float_as_uint(r2) >> 16);
}

// ---- 8 spike bits -> short8 of bf16 {0,1} (element e = bit e) ----
__device__ inline short8 expand8(unsigned x) {
    union { unsigned u[4]; short8 v; } r;
#pragma unroll
    for (int q = 0; q < 4; ++q) {
        unsigned b = x >> (2 * q);
        r.u[q] = ((b & 1u) * 0x3F80u) | ((b & 2u) ? 0x3F800000u : 0u);
    }
    return r.v;
}

// ---- split weights: W2S[pi][p][i][q] (j=2q+p), W3S[pi][c][i][q] (j=c+3q) ----
__global__ __launch_bounds__(256) void kSplit(
    const float* __restrict__ W2, const float* __restrict__ W3,
    ushort* __restrict__ W2S, ushort* __restrict__ W3S)
{
    int id = blockIdx.x * 256 + threadIdx.x;
    if (id < 1048576) {
        int p = id >> 19, rem = id & 524287, i = rem >> 9, q = rem & 511;
        ushort h, m, l;
        split3(W2[i * 1024 + 2 * q + p], h, m, l);
        size_t base = (size_t)p * 524288 + (size_t)i * 512 + q;
        W2S[base] = h; W2S[base + 1048576] = m; W2S[base + 2097152] = l;
    } else {
        int id2 = id - 1048576;
        if (id2 >= 1056768) return;
        int c = id2 / 352256, rem = id2 % 352256, i = rem / 344, q = rem % 344;
        int j = c + 3 * q;
        float w = (j < 1024) ? W3[i * 1024 + j] : 0.f;
        ushort h, m, l;
        split3(w, h, m, l);
        W3S[id2] = h; W3S[id2 + 1056768] = m; W3S[id2 + 2113536] = l;
    }
}

// ---- transpose input -> xT[784][1024] ----
__global__ __launch_bounds__(256) void kPrep(const float* __restrict__ input,
                                             float* __restrict__ xT)
{
    __shared__ float Ls[64][65];
    int bx = blockIdx.x, tid = threadIdx.x;
    int wt = bx >> 4, nt = bx & 15;
    int w0 = wt * 64, n0 = nt * 64;
#pragma unroll
    for (int j = 0; j < 16; ++j) {
        int flat = tid + 256 * j;
        int a = flat >> 6, c = flat & 63;
        Ls[a][c] = (w0 + c < 784) ? input[(size_t)(n0 + a) * 784 + w0 + c] : 0.f;
    }
    __syncthreads();
#pragma unroll
    for (int j = 0; j < 16; ++j) {
        int flat = tid + 256 * j;
        int ii = flat >> 6, nn = flat & 63;
        if (w0 + ii < 784) xT[(size_t)(w0 + ii) * 1024 + n0 + nn] = Ls[nn][ii];
    }
}

// ---- layer-1: phase A (t<12, varying window) + phase B (t>=12, constant window) ----
__global__ __launch_bounds__(256) void kL1(
    const float* __restrict__ xT, const float* __restrict__ W1,
    const float* __restrict__ b1,
    unsigned long long* __restrict__ s1bits, float* __restrict__ ss1)
{
    int tid = threadIdx.x;
    int waveId = (blockIdx.x << 2) + (tid >> 6);   // 0..4095
    int lane = tid & 63;
    int rowg = waveId >> 4;                        // 0..255
    int nblk = waveId & 15;
    int i0 = rowg << 2;
    int n = (nblk << 6) + lane;
    float w[4][8], bb[4], mem[4], cnt[4];
#pragma unroll
    for (int r = 0; r < 4; ++r) {
#pragma unroll
        for (int e = 0; e < 8; ++e) w[r][e] = W1[(i0 + r) * 8 + e];
        bb[r] = b1[i0 + r]; mem[r] = 0.f; cnt[r] = 0.f;
    }
    float x[8], xn[8];
#pragma unroll
    for (int e = 0; e < 8; ++e) x[e] = xT[(size_t)e * 1024 + n];
    for (int t = 0; t < 12; ++t) {
        int st1 = ((t + 1) * 8 < TTL - 8) ? (t + 1) * 8 : (784 - 8);
#pragma unroll
        for (int e = 0; e < 8; ++e) xn[e] = xT[(size_t)(st1 + e) * 1024 + n];
#pragma unroll
        for (int r = 0; r < 4; ++r) {
            if (((t ^ (i0 + r)) & 1) == 0) {       // parity rule exact for cycle 2 (98 even)
                float d = bb[r];
#pragma unroll
                for (int e = 0; e < 8; ++e) d += w[r][e] * x[e];
                float m = mem[r] * 0.5f + d;       // prev spike provably 0 at active steps
                mem[r] = m;
                bool sp = m > 0.5f;
                unsigned long long bm = __ballot(sp);
                if (lane == 0) s1bits[(size_t)(t * 512 + ((i0 + r) >> 1)) * 16 + nblk] = bm;
                if (sp) cnt[r] += 1.f;
            }
        }
#pragma unroll
        for (int e = 0; e < 8; ++e) x[e] = xn[e];
    }
    float dd[4];
#pragma unroll
    for (int r = 0; r < 4; ++r) {
        float d = bb[r];
#pragma unroll
        for (int e = 0; e < 8; ++e) d += w[r][e] * x[e];
        dd[r] = d;
    }
#pragma unroll 1
    for (int t = 12; t < TTL; t += 2) {            // t even: rows 0,2 ; t+1: rows 1,3
#pragma unroll
        for (int h = 0; h < 2; ++h) {
#pragma unroll
            for (int rr = 0; rr < 2; ++rr) {
                int r = h + rr * 2;
                float m = mem[r] * 0.5f + dd[r];
                mem[r] = m;
                bool sp = m > 0.5f;
                unsigned long long bm = __ballot(sp);
                if (lane == 0) s1bits[(size_t)((t + h) * 512 + ((i0 + r) >> 1)) * 16 + nblk] = bm;
                if (sp) cnt[r] += 1.f;
            }
        }
    }
#pragma unroll
    for (int r = 0; r < 4; ++r) ss1[(size_t)(i0 + r) * 1024 + n] = cnt[r];
}

// ---- per-t tables via prefix scan: u=(t-i) mod 98 (98%3,4 != 0 -> table, not residue) ----
__global__ __launch_bounds__(256) void kTab2(
    int* __restrict__ idx2, int* __restrict__ idx3, int* __restrict__ cq3)
{
    __shared__ int f2[256], f3[256];
    __shared__ int sidx2[384], sidx3[320];
    int t = blockIdx.x, tid = threadIdx.x;
    int a2[4], a3[4];
    int l2 = 0, l3 = 0;
#pragma unroll
    for (int e = 0; e < 4; ++e) {
        int i = tid * 4 + e;
        int u = (t - i) % TTL; if (u < 0) u += TTL;
        a2[e] = (u % 3 == 0); a3[e] = (u % 4 == 0);
        l2 += a2[e]; l3 += a3[e];
    }
    f2[tid] = l2; f3[tid] = l3;
    __syncthreads();
    for (int s = 1; s < 256; s <<= 1) {
        int v2 = (tid >= s) ? f2[tid - s] : 0;
        int v3 = (tid >= s) ? f3[tid - s] : 0;
        __syncthreads();
        f2[tid] += v2; f3[tid] += v3;
        __syncthreads();
    }
    int o2 = f2[tid] - l2, o3 = f3[tid] - l3;
    int c2 = f2[255], c3 = f3[255];
#pragma unroll
    for (int e = 0; e < 4; ++e) {
        int i = tid * 4 + e;
        if (a2[e]) { sidx2[o2] = i; ++o2; }
        if (a3[e]) { sidx3[o3] = i; ++o3; }
    }
    __syncthreads();
    for (int k = tid; k < 384; k += 256) idx2[t * 384 + k] = (k < c2) ? sidx2[k] : -1;
    for (int k = tid; k < 320; k += 256) idx3[t * 320 + k] = (k < c3) ? sidx3[k] : -1;
    for (int k = tid; k < 352; k += 256) {
        int j = (k < c2) ? sidx2[k] : 0;
        cq3[t * 352 + k] = (j % 3) * 352256 + j / 3;
    }
}

// ---- closed-form per-row activation lists ----
template<int C, int NACT>
__global__ __launch_bounds__(256) void kListCF(int* __restrict__ list)
{
    int flat = blockIdx.x * 256 + threadIdx.x;      // row*NACT + s
    if (flat >= 1024 * NACT) return;
    int i = flat / NACT, s = flat % NACT;
    int ri = i % 98;
    int k0 = (98 - ri + C - 1) / C;                 // first wrapped k
    int kw = NACT - k0; if (kw < 0) kw = 0;
    int t = (s < kw) ? (ri + (k0 + s) * C - 98) : (ri + (s - kw) * C);
    int rk = 0;
    int r = t;
#pragma unroll
    for (int k = 0; k < NACT; ++k) {
        rk += (r < i) ? (i - r + 97) / 98 : 0;      // count of i'<i with i'≡r (mod 98)
        r -= C; if (r < 0) r += 98;
    }
    list[i * NACT + s] = (t << 10) | rk;
}

// ---- bit-matrix transpose (layer-1, full range): [t][k][nw] -> [t][kw][n] ----
template<int K>
__global__ __launch_bounds__(256) void kXb(const unsigned* __restrict__ in,
                                           unsigned* __restrict__ out, int t0)
{
    constexpr int Kw = K / 32;
    __shared__ unsigned L[1024];
    int bx = blockIdx.x, tid = threadIdx.x;
    int tt = t0 + bx / Kw, kw = bx % Kw;
    const unsigned* ip = in + ((size_t)tt * K + kw * 32) * 32;
#pragma unroll
    for (int g = 0; g < 4; ++g) L[g * 256 + tid] = ip[g * 256 + tid];
    __syncthreads();
    unsigned* op = out + ((size_t)tt * Kw + kw) * 1024;
#pragma unroll
    for (int g = 0; g < 4; ++g) {
        int n = g * 256 + tid;
        int w = n >> 5, b = n & 31;
        unsigned acc = 0;
#pragma unroll
        for (int k = 0; k < 32; ++k) acc |= ((L[k * 32 + w] >> b) & 1u) << k;
        op[n] = acc;
    }
}

// ---- fused per-chunk: layer-2 bit transpose (11 blocks/t) + layer-3 A-gather (55 blocks/t) ----
__global__ __launch_bounds__(256) void kXbG3A(
    const unsigned* __restrict__ s2b, unsigned* __restrict__ s2bT,
    const ushort* __restrict__ Ws, const int* __restrict__ idx3,
    const int* __restrict__ cq3, ushort* __restrict__ AW3, int t0)
{
    __shared__ unsigned L[1024];
    int bx = blockIdx.x, tid = threadIdx.x;
    int tloc = bx / 66, r66 = bx % 66;
    int t = t0 + tloc;
    if (r66 < 11) {
        int kw = r66;
        const unsigned* ip = s2b + ((size_t)t * 352 + kw * 32) * 32;
#pragma unroll
        for (int g = 0; g < 4; ++g) L[g * 256 + tid] = ip[g * 256 + tid];
        __syncthreads();
        unsigned* op = s2bT + ((size_t)t * 11 + kw) * 1024;
#pragma unroll
        for (int g = 0; g < 4; ++g) {
            int n = g * 256 + tid;
            int w = n >> 5, b = n & 31;
            unsigned acc = 0;
#pragma unroll
            for (int k = 0; k < 32; ++k) acc |= ((L[k * 32 + w] >> b) & 1u) << k;
            op[n] = acc;
        }
    } else {
        int blk = r66 - 11;
        int flat = blk * 256 + tid;      // 0..14079 = 320 rows * 44 k-groups
        int r = flat / 44, kg = flat % 44;
        int k0 = kg * 8;
        int v = idx3[t * 320 + r];
        int i = v < 0 ? 0 : v;           // pad rows: garbage, never read back
        const int* cq = cq3 + t * 352 + k0;
        int c0 = cq[0], c1 = cq[1], c2 = cq[2], c3 = cq[3],
            c4 = cq[4], c5 = cq[5], c6 = cq[6], c7 = cq[7];
        size_t ia = (size_t)i * 344;
#pragma unroll
        for (int pi = 0; pi < 3; ++pi) {
            const ushort* wp = Ws + (size_t)pi * 1056768 + ia;
            union { ushort us[8]; ul2 v2; } o;
            o.us[0] = wp[c0]; o.us[1] = wp[c1]; o.us[2] = wp[c2]; o.us[3] = wp[c3];
            o.us[4] = wp[c4]; o.us[5] = wp[c5]; o.us[6] = wp[c6]; o.us[7] = wp[c7];
            *(ul2*)(AW3 + ((size_t)tloc * 3 + pi) * 112640 + (size_t)r * 352 + k0) = o.v2;
        }
    }
}

// ==================== GEMM bodies: barrier-free, A-fragments direct from global ====================
// Each lane's MFMA A-fragment is 8 contiguous bf16 = one 16B load; no cross-lane
// redistribution needed, so LDS staging + __syncthreads were pure overhead (convoy).
// Sibling nt4-blocks and waves re-read the same 64B lines -> L2-hot.
// MFMA order per acc element unchanged (kc -> s2 -> af2,af1,af0 -> jj): bit-exact.

__device__ __forceinline__ void gm2_body(
    int bx, int tid,
    const ushort* __restrict__ Ws, const unsigned* __restrict__ s1bT,
    const int* __restrict__ idx2, float* __restrict__ drive, int t0)
{
    int tloc = bx / 24, rem = bx % 24;
    int mt = rem >> 2, nt4 = rem & 3;
    int t = t0 + tloc;
    int p = t & 1;
    int r0 = mt * 64, n0 = nt4 * 256;
    int wv = tid >> 6, lane = tid & 63;
    int mrow = lane & 31, kh8 = (lane >> 5) * 8;
    int nb = n0 + wv * 64 + mrow;
    int vR0 = idx2[t * 384 + r0 + mrow];
    int vR1 = idx2[t * 384 + r0 + 32 + mrow];
    const ushort* Ar[2];
    Ar[0] = Ws + (size_t)p * 524288 + (size_t)(vR0 < 0 ? 0 : vR0) * 512 + kh8;
    Ar[1] = Ws + (size_t)p * 524288 + (size_t)(vR1 < 0 ? 0 : vR1) * 512 + kh8;
    f16v acc[2][2];
#pragma unroll
    for (int a = 0; a < 2; ++a)
#pragma unroll
        for (int b = 0; b < 2; ++b) acc[a][b] = (f16v)(0.f);

    short8 fc[2][2][3];                 // [s2][wr2][pi] current K-step fragments
#pragma unroll
    for (int s2 = 0; s2 < 2; ++s2)
#pragma unroll
        for (int wr2 = 0; wr2 < 2; ++wr2)
#pragma unroll
            for (int pi = 0; pi < 3; ++pi)
                fc[s2][wr2][pi] = *(const short8*)(Ar[wr2] + (size_t)pi * 1048576 + s2 * 16);
    unsigned w4c[2];
#pragma unroll
    for (int jj = 0; jj < 2; ++jj) w4c[jj] = s1bT[(size_t)t * 16 * 1024 + nb + jj * 32];

#pragma unroll 1
    for (int kc = 0; kc < 512; kc += 32) {
        short8 fn[2][2][3];
        unsigned w4n[2];
        if (kc + 32 < 512) {
#pragma unroll
            for (int s2 = 0; s2 < 2; ++s2)
#pragma unroll
                for (int wr2 = 0; wr2 < 2; ++wr2)
#pragma unroll
                    for (int pi = 0; pi < 3; ++pi)
                        fn[s2][wr2][pi] = *(const short8*)(Ar[wr2] + (size_t)pi * 1048576 + kc + 32 + s2 * 16);
#pragma unroll
            for (int jj = 0; jj < 2; ++jj)
                w4n[jj] = s1bT[((size_t)t * 16 + ((kc + 32) >> 5)) * 1024 + nb + jj * 32];
        }
#pragma unroll
        for (int s2 = 0; s2 < 2; ++s2) {
            int kcol = s2 * 16 + kh8;
            short8 bf[2];
#pragma unroll
            for (int jj = 0; jj < 2; ++jj) bf[jj] = expand8((w4c[jj] >> kcol) & 0xFFu);
#pragma unroll
            for (int wr2 = 0; wr2 < 2; ++wr2) {
#pragma unroll
                for (int jj = 0; jj < 2; ++jj) {
                    acc[wr2][jj] = __builtin_amdgcn_mfma_f32_32x32x16_bf16(fc[s2][wr2][2], bf[jj], acc[wr2][jj], 0, 0, 0);
                    acc[wr2][jj] = __builtin_amdgcn_mfma_f32_32x32x16_bf16(fc[s2][wr2][1], bf[jj], acc[wr2][jj], 0, 0, 0);
                    acc[wr2][jj] = __builtin_amdgcn_mfma_f32_32x32x16_bf16(fc[s2][wr2][0], bf[jj], acc[wr2][jj], 0, 0, 0);
                }
            }
        }
#pragma unroll
        for (int s2 = 0; s2 < 2; ++s2)
#pragma unroll
            for (int wr2 = 0; wr2 < 2; ++wr2)
#pragma unroll
                for (int pi = 0; pi < 3; ++pi) fc[s2][wr2][pi] = fn[s2][wr2][pi];
        w4c[0] = w4n[0]; w4c[1] = w4n[1];
    }
#pragma unroll
    for (int wr2 = 0; wr2 < 2; ++wr2)
#pragma unroll
        for (int jj = 0; jj < 2; ++jj)
#pragma unroll
            for (int reg = 0; reg < 16; ++reg) {
                int rowl = r0 + wr2 * 32 + (reg & 3) + 8 * (reg >> 2) + 4 * (lane >> 5);
                drive[((size_t)tloc * 384 + rowl) * 1024 + nb + jj * 32] = acc[wr2][jj][reg];
            }
}

__device__ __forceinline__ void gm3_body(
    int bx, int tid,
    const ushort* __restrict__ AW3, const unsigned* __restrict__ s2bT,
    float* __restrict__ drive, int t0)
{
    int tloc = bx / 20, rem = bx % 20;
    int mt = rem >> 2, nt4 = rem & 3;
    int t = t0 + tloc;
    int r0 = mt * 64, n0 = nt4 * 256;
    int wv = tid >> 6, lane = tid & 63;
    int mrow = lane & 31, kh8 = (lane >> 5) * 8;
    int nb = n0 + wv * 64 + mrow;
    const ushort* Ar[2];
    Ar[0] = AW3 + (size_t)tloc * 337920 + (size_t)(r0 + mrow) * 352 + kh8;
    Ar[1] = AW3 + (size_t)tloc * 337920 + (size_t)(r0 + 32 + mrow) * 352 + kh8;
    f16v acc[2][2];
#pragma unroll
    for (int a = 0; a < 2; ++a)
#pragma unroll
        for (int b = 0; b < 2; ++b) acc[a][b] = (f16v)(0.f);

    short8 fc[2][2][3];
#pragma unroll
    for (int s2 = 0; s2 < 2; ++s2)
#pragma unroll
        for (int wr2 = 0; wr2 < 2; ++wr2)
#pragma unroll
            for (int pi = 0; pi < 3; ++pi)
                fc[s2][wr2][pi] = *(const short8*)(Ar[wr2] + (size_t)pi * 112640 + s2 * 16);
    unsigned w4c[2];
#pragma unroll
    for (int jj = 0; jj < 2; ++jj) w4c[jj] = s2bT[(size_t)t * 11 * 1024 + nb + jj * 32];

#pragma unroll 1
    for (int kc = 0; kc < 352; kc += 32) {
        short8 fn[2][2][3];
        unsigned w4n[2];
        if (kc + 32 < 352) {
#pragma unroll
            for (int s2 = 0; s2 < 2; ++s2)
#pragma unroll
                for (int wr2 = 0; wr2 < 2; ++wr2)
#pragma unroll
                    for (int pi = 0; pi < 3; ++pi)
                        fn[s2][wr2][pi] = *(const short8*)(Ar[wr2] + (size_t)pi * 112640 + kc + 32 + s2 * 16);
#pragma unroll
            for (int jj = 0; jj < 2; ++jj)
                w4n[jj] = s2bT[((size_t)t * 11 + ((kc + 32) >> 5)) * 1024 + nb + jj * 32];
        }
#pragma unroll
        for (int s2 = 0; s2 < 2; ++s2) {
            int kcol = s2 * 16 + kh8;
            short8 bf[2];
#pragma unroll
            for (int jj = 0; jj < 2; ++jj) bf[jj] = expand8((w4c[jj] >> kcol) & 0xFFu);
#pragma unroll
            for (int wr2 = 0; wr2 < 2; ++wr2) {
#pragma unroll
                for (int jj = 0; jj < 2; ++jj) {
                    acc[wr2][jj] = __builtin_amdgcn_mfma_f32_32x32x16_bf16(fc[s2][wr2][2], bf[jj], acc[wr2][jj], 0, 0, 0);
                    acc[wr2][jj] = __builtin_amdgcn_mfma_f32_32x32x16_bf16(fc[s2][wr2][1], bf[jj], acc[wr2][jj], 0, 0, 0);
                    acc[wr2][jj] = __builtin_amdgcn_mfma_f32_32x32x16_bf16(fc[s2][wr2][0], bf[jj], acc[wr2][jj], 0, 0, 0);
                }
            }
        }
#pragma unroll
        for (int s2 = 0; s2 < 2; ++s2)
#pragma unroll
            for (int wr2 = 0; wr2 < 2; ++wr2)
#pragma unroll
                for (int pi = 0; pi < 3; ++pi) fc[s2][wr2][pi] = fn[s2][wr2][pi];
        w4c[0] = w4n[0]; w4c[1] = w4n[1];
    }
#pragma unroll
    for (int wr2 = 0; wr2 < 2; ++wr2)
#pragma unroll
        for (int jj = 0; jj < 2; ++jj)
#pragma unroll
            for (int reg = 0; reg < 16; ++reg) {
                int rowl = r0 + wr2 * 32 + (reg & 3) + 8 * (reg >> 2) + 4 * (lane >> 5);
                drive[((size_t)tloc * 320 + rowl) * 1024 + nb + jj * 32] = acc[wr2][jj][reg];
            }
}

// standalone wrappers (prologue GM2 / epilogue GM3)
__global__ __launch_bounds__(256) void kGM2K(
    const ushort* __restrict__ Ws, const unsigned* __restrict__ s1bT,
    const int* __restrict__ idx2, float* __restrict__ drive, int t0)
{
    gm2_body(blockIdx.x, threadIdx.x, Ws, s1bT, idx2, drive, t0);
}
__global__ __launch_bounds__(256) void kGM3K(
    const ushort* __restrict__ AW3, const unsigned* __restrict__ s2bT,
    float* __restrict__ drive, int t0)
{
    gm3_body(blockIdx.x, threadIdx.x, AW3, s2bT, drive, t0);
}

// fused cross-chunk GEMM: GM2(chunk c+1) blocks first (longer, LPT), then GM3(chunk c)
__global__ __launch_bounds__(256) void kGMF(
    const ushort* __restrict__ W2S, const unsigned* __restrict__ s1bT,
    const int* __restrict__ idx2, float* __restrict__ drv2, int t0_2, int n2blocks,
    const ushort* __restrict__ AW3, const unsigned* __restrict__ s2bT,
    float* __restrict__ drv3, int t0_3)
{
    int bx = blockIdx.x;
    if (bx < n2blocks) gm2_body(bx, threadIdx.x, W2S, s1bT, idx2, drv2, t0_2);
    else               gm3_body(bx - n2blocks, threadIdx.x, AW3, s2bT, drv3, t0_3);
}

// ---- chunk recurrence body: one wave per (row, 64-col block), depth-2 drive prefetch ----
template<int MP, int KBP, bool BITS, int NACT>
__device__ __forceinline__ void rk_body(
    int bx, int tid,
    const float* __restrict__ drive, const float* __restrict__ bias,
    const int* __restrict__ list,
    float* __restrict__ mG, float* __restrict__ ssG,
    unsigned long long* __restrict__ bitsOut, int t0, int nt)
{
    int row = bx >> 2;                               // 0..1023
    int wv  = ((bx & 3) << 2) + (tid >> 6);          // nblk 0..15
    int lane = tid & 63;
    int n = (wv << 6) + lane;
    size_t idx = (size_t)row * 1024 + n;
    float mv = mG[idx];
    float cnt = 0.f;
    float bv = bias[row];
    const int* lp = list + row * NACT;               // wave-uniform -> scalar loads
    int t1 = t0 + nt;
    int s0 = 0;
    while (s0 < NACT && (lp[s0] >> 10) < t0) ++s0;
    int s1 = s0;
    while (s1 < NACT && (lp[s1] >> 10) < t1) ++s1;
    if (s0 < s1) {
        int v0 = lp[s0];
        float d0 = drive[((size_t)((v0 >> 10) - t0) * MP + (v0 & 1023)) * 1024 + n];
        int v1 = 0; float d1 = 0.f;
        if (s0 + 1 < s1) {
            v1 = lp[s0 + 1];
            d1 = drive[((size_t)((v1 >> 10) - t0) * MP + (v1 & 1023)) * 1024 + n];
        }
        for (int s = s0; s < s1; ++s) {
            int vc = v0;
            float dcur = d0;
            v0 = v1; d0 = d1;
            if (s + 2 < s1) {
                v1 = lp[s + 2];
                d1 = drive[((size_t)((v1 >> 10) - t0) * MP + (v1 & 1023)) * 1024 + n];
            }
            float d = dcur + bv;
            float m = mv * 0.5f + d;
            mv = m;
            bool sp = m > 0.5f;
            if (BITS) {
                unsigned long long bm = __ballot(sp);
                if (lane == 0) bitsOut[((size_t)(vc >> 10) * KBP + (vc & 1023)) * 16 + wv] = bm;
            }
            cnt += sp ? 1.f : 0.f;
        }
    }
    mG[idx] = mv;
    ssG[idx] += cnt;
}

template<int MP, int KBP, bool BITS, int NACT>
__global__ __launch_bounds__(256) void kRK(
    const float* __restrict__ drive, const float* __restrict__ bias,
    const int* __restrict__ list,
    float* __restrict__ mG, float* __restrict__ ssG,
    unsigned long long* __restrict__ bitsOut, int t0, int nt)
{
    rk_body<MP, KBP, BITS, NACT>(blockIdx.x, threadIdx.x, drive, bias, list,
                                 mG, ssG, bitsOut, t0, nt);
}

// fused cross-chunk recurrence: RK3(chunk c) [4096 blocks] + RK2(chunk c+1) [4096 blocks]
__global__ __launch_bounds__(256) void kRKF(
    const float* __restrict__ drv3, const float* __restrict__ b3,
    const int* __restrict__ list3, float* __restrict__ m3, float* __restrict__ ss3,
    int t0_3, int nt3,
    const float* __restrict__ drv2, const float* __restrict__ b2,
    const int* __restrict__ list2, float* __restrict__ m2, float* __restrict__ ss2,
    unsigned long long* __restrict__ s2bits, int t0_2, int nt2)
{
    int bx = blockIdx.x;
    if (bx < 4096)
        rk_body<320, 0, false, 25>(bx, threadIdx.x, drv3, b3, list3, m3, ss3,
                                   nullptr, t0_3, nt3);
    else
        rk_body<384, 352, true, 33>(bx - 4096, threadIdx.x, drv2, b2, list2, m2, ss2,
                                    s2bits, t0_2, nt2);
}

// ---- tail: ss transposes + fr; W4 GEMV partials into osum ----
__global__ __launch_bounds__(256) void kTail(
    const float* __restrict__ ssBase, const float* __restrict__ W4,
    float* __restrict__ osum, float* __restrict__ out, float* __restrict__ fr)
{
    int bx = blockIdx.x, tid = threadIdx.x;
    if (bx < 768) {
        __shared__ float Ls[64][65];
        __shared__ float red[4];
        int l = bx >> 8;
        int tile = bx & 255;
        int i0 = (tile >> 4) * 64, n0 = (tile & 15) * 64;
        const float* ss = ssBase + (size_t)l * MM;
        float* o = out + 10240 + (size_t)l * MM;
        float sum = 0.f;
#pragma unroll
        for (int j = 0; j < 16; ++j) {
            int flat = tid + 256 * j;
            int a = flat >> 6, c = flat & 63;
            float v = ss[(size_t)(i0 + a) * 1024 + n0 + c];
            Ls[a][c] = v;
            sum += v;
        }
        __syncthreads();
        for (int off = 32; off > 0; off >>= 1) sum += __shfl_down(sum, off, 64);
        if ((tid & 63) == 0) red[tid >> 6] = sum;
        __syncthreads();
        if (tid == 0) {
            float s = red[0] + red[1] + red[2] + red[3];
            atomicAdd(&fr[l], s * (1.0f / (1024.0f * 1024.0f * 98.0f)));
        }
#pragma unroll
        for (int j = 0; j < 16; ++j) {
            int flat = tid + 256 * j;
            int nn = flat >> 6, ii = flat & 63;
            o[(size_t)(n0 + nn) * 1024 + i0 + ii] = Ls[ii][nn] * (1.0f / 98.0f);
        }
    } else {
        int b = bx - 768;
        int ks = b >> 4, nt = b & 15;
        int n = nt * 64 + (tid & 63);
        int og = tid >> 6;
        const float* ss3 = ssBase + (size_t)2 * MM;
        float a0 = 0.f, a1 = 0.f, a2 = 0.f;
        int k0 = ks * 256;
        for (int k = k0; k < k0 + 256; ++k) {
            float v = ss3[(size_t)k * 1024 + n];
            a0 += v * W4[og * 1024 + k];
            a1 += v * W4[(og + 4) * 1024 + k];
            if (og < 2) a2 += v * W4[(og + 8) * 1024 + k];
        }
        atomicAdd(&osum[n * OUTD + og], a0);
        atomicAdd(&osum[n * OUTD + og + 4], a1);
        if (og < 2) atomicAdd(&osum[n * OUTD + og + 8], a2);
    }
}

__global__ void kOut(const float* __restrict__ osum, const float* __restrict__ b4,
                     float* __restrict__ out)
{
    int idx = blockIdx.x * 256 + threadIdx.x;
    if (idx < 1024 * OUTD) out[idx] = osum[idx] * (1.0f / 98.0f) + b4[idx % OUTD];
}

extern "C" void kernel_launch(void* const* d_in, const int* in_sizes, int n_in,
                              void* d_out, int out_size, void* d_ws, size_t ws_size,
                              hipStream_t stream)
{
    const float* input = (const float*)d_in[0];
    const float* W1    = (const float*)d_in[1];
    const float* b1    = (const float*)d_in[2];
    const float* W2    = (const float*)d_in[3];
    const float* b2    = (const float*)d_in[4];
    const float* W3    = (const float*)d_in[5];
    const float* b3    = (const float*)d_in[6];
    const float* W4    = (const float*)d_in[7];
    const float* b4    = (const float*)d_in[8];

    float* ws = (float*)d_ws;
    float* ss1  = ws;
    float* ss2  = ws + MM;
    float* ss3  = ws + 2 * MM;
    float* m2   = ws + 3 * MM;
    float* m3   = ws + 4 * MM;
    float* osum = ws + OFF_OSUM;
    float* xT   = ws + OFF_XT;
    int*   tabs = (int*)(ws + OFF_XT);   // reuses xT region after kL1
    int* idx2  = tabs + TAB_IDX2;
    int* idx3  = tabs + TAB_IDX3;
    int* cq3   = tabs + TAB_CQ3;
    int* list2 = tabs + TAB_L2;
    int* list3 = tabs + TAB_L3;
    unsigned int* s1b  = (unsigned int*)(ws + OFF_S1B);
    unsigned int* s2b  = (unsigned int*)(ws + OFF_S2B);
    unsigned int* s1bT = (unsigned int*)(ws + OFF_S1BT);
    unsigned int* s2bT = (unsigned int*)(ws + OFF_S2BT);
    ushort* W2S = (ushort*)(ws + OFF_W2S);
    ushort* W3S = (ushort*)(ws + OFF_W3S);
    float* out  = (float*)d_out;

    // pick the largest t-chunk the workspace can hold.
    size_t availF = ws_size / sizeof(float);
    constexpr size_t PER_T = AW3_PER_T + 384 * 1024 + 320 * 1024;   // 889,856 floats
    int tc = 10;   // guaranteed-fit fallback (~94 MB)
    const int cands[8] = {98, 66, 49, 40, 33, 25, 14, 10};
    for (int ci = 0; ci < 8; ++ci) {
        if (FIX_END + (size_t)cands[ci] * PER_T <= availF) { tc = cands[ci]; break; }
    }
    ushort* AW3 = (ushort*)(ws + FIX_END);
    float* drv2 = ws + FIX_END + (size_t)tc * AW3_PER_T;
    float* drv3 = drv2 + (size_t)tc * 384 * 1024;

    hipMemsetAsync(ws, 0, (5 * MM + 10240) * sizeof(float), stream);   // ss, m2, m3, osum
    hipMemsetAsync(s2b, 0, 1103872 * sizeof(unsigned int), stream);    // layer-2 bits (pad ranks)
    hipMemsetAsync(out + 3155968, 0, 3 * sizeof(float), stream);       // fr

    kSplit<<<8224, 256, 0, stream>>>(W2, W3, W2S, W3S);
    kPrep<<<208, 256, 0, stream>>>(input, xT);
    kL1<<<1024, 256, 0, stream>>>(xT, W1, b1, (unsigned long long*)s1b, ss1);
    kTab2<<<98, 256, 0, stream>>>(idx2, idx3, cq3);                    // after kL1: reuses xT mem
    kListCF<3, 33><<<132, 256, 0, stream>>>(list2);
    kListCF<4, 25><<<100, 256, 0, stream>>>(list3);
    kXb<512><<<1568, 256, 0, stream>>>(s1b, s1bT, 0);

    int nc = (TTL + tc - 1) / tc;
    auto ntOf = [&](int c) { int t0c = c * tc; return (TTL - t0c < tc) ? (TTL - t0c) : tc; };

    // software pipeline with cross-chunk fusion:
    //   GM2(0), RK2(0), X(0), { GMF[GM2(c+1)+GM3(c)], RKF[RK3(c)+RK2(c+1)], X(c+1) }, GM3(last), RK3(last)
    kGM2K<<<ntOf(0) * 24, 256, 0, stream>>>(W2S, s1bT, idx2, drv2, 0);
    kRK<384, 352, true, 33><<<4096, 256, 0, stream>>>(drv2, b2, list2, m2, ss2,
                                                      (unsigned long long*)s2b, 0, ntOf(0));
    kXbG3A<<<ntOf(0) * 66, 256, 0, stream>>>(s2b, s2bT, W3S, idx3, cq3, AW3, 0);

    for (int c = 0; c + 1 < nc; ++c) {
        int t03 = c * tc, t02 = (c + 1) * tc;
        int n2b = ntOf(c + 1) * 24, n3b = ntOf(c) * 20;
        kGMF<<<n2b + n3b, 256, 0, stream>>>(W2S, s1bT, idx2, drv2, t02, n2b,
                                            AW3, s2bT, drv3, t03);
        kRKF<<<8192, 256, 0, stream>>>(drv3, b3, list3, m3, ss3, t03, ntOf(c),
                                       drv2, b2, list2, m2, ss2,
                                       (unsigned long long*)s2b, t02, ntOf(c + 1));
        kXbG3A<<<ntOf(c + 1) * 66, 256, 0, stream>>>(s2b, s2bT, W3S, idx3, cq3, AW3, t02);
    }
    int cl = nc - 1, t0l = cl * tc;
    kGM3K<<<ntOf(cl) * 20, 256, 0, stream>>>(AW3, s2bT, drv3, t0l);
    kRK<320, 0, false, 25><<<4096, 256, 0, stream>>>(drv3, b3, list3, m3, ss3,
                                                     nullptr, t0l, ntOf(cl));

    kTail<<<832, 256, 0, stream>>>(ss1, W4, osum, out, out + 3155968);
    kOut<<<40, 256, 0, stream>>>(osum, b4, out);
}

// Round 13
// 624.671 us; speedup vs baseline: 1.0824x; 1.0824x over previous
//
#include <hip/hip_runtime.h>

#define TTL 98
#define OUTD 10

typedef float f16v __attribute__((ext_vector_type(16)));
typedef short short8 __attribute__((ext_vector_type(8)));
typedef unsigned long ul2 __attribute__((ext_vector_type(2)));
typedef unsigned short ushort;

constexpr size_t MM = 1048576;
constexpr size_t OFF_OSUM = 5 * MM;                  // 10,240
constexpr size_t OFF_XT   = OFF_OSUM + 10240;        // 802,816 (tables reuse after kL1)
constexpr size_t OFF_S1B  = OFF_XT + 802816;         // u32: 98*512*32
constexpr size_t OFF_S2B  = OFF_S1B + 1605632;       // u32: 98*352*32
constexpr size_t OFF_S1BT = OFF_S2B + 1103872;       // u32: 98*16*1024 (bit-transposed L1)
constexpr size_t OFF_S2BT = OFF_S1BT + 1605632;      // u32: 98*11*1024 (bit-transposed L2)
constexpr size_t OFF_W2S  = OFF_S2BT + 1103872;      // bf16 3*2*1024*512
constexpr size_t OFF_W3S  = OFF_W2S + 1572864;       // bf16 3*3*1024*344
constexpr size_t FIX_END  = OFF_W3S + 1585152;       // 14,632,960 floats (58.5 MB)

constexpr size_t TAB_IDX2 = 0;        // 98*384
constexpr size_t TAB_IDX3 = 37632;    // 98*320
constexpr size_t TAB_CQ3  = 269696;   // 98*352
constexpr size_t TAB_L2   = 304192;   // 1024*33 packed (t<<10|rk), exactly 33 per row
constexpr size_t TAB_L3   = 337984;   // 1024*25 packed, exactly 25 per row

// AW3 per-t footprint: 3 * 320 * 352 ushort = 337,920 ushort = 168,960 floats (FULL size).
constexpr size_t AW3_PER_T = 168960;

// ---- exact 3-way bf16 split by truncation: hi+mid+lo == w bit-exactly ----
__device__ inline void split3(float w, ushort& h, ushort& m, ushort& l) {
    unsigned u = __float_as_uint(w);
    h = (ushort)(u >> 16);
    float r1 = w - __uint_as_float(u & 0xFFFF0000u);
    unsigned u1 = __float_as_uint(r1);
    m = (ushort)(u1 >> 16);
    float r2 = r1 - __uint_as_float(u1 & 0xFFFF0000u);
    l = (ushort)(__float_as_uint(r2) >> 16);
}

// ---- 8 spike bits -> short8 of bf16 {0,1} (element e = bit e) ----
__device__ inline short8 expand8(unsigned x) {
    union { unsigned u[4]; short8 v; } r;
#pragma unroll
    for (int q = 0; q < 4; ++q) {
        unsigned b = x >> (2 * q);
        r.u[q] = ((b & 1u) * 0x3F80u) | ((b & 2u) ? 0x3F800000u : 0u);
    }
    return r.v;
}

// ---- LDS helpers: 72B-stride rows -> b64 pairs ----
__device__ inline short8 ldsAF(const ushort* base) {
    union { unsigned long u[2]; short8 s; } r;
    r.u[0] = *(const unsigned long*)(base);
    r.u[1] = *(const unsigned long*)(base + 4);
    return r.s;
}
__device__ inline void ldsWR(ushort* dst, ul2 v) {
    *(unsigned long*)(dst) = v[0];
    *(unsigned long*)(dst + 4) = v[1];
}
// As layout (raw): [cur][pi][row][col36]
#define ASOFF(cur, pi, row, col) (((((cur)*3 + (pi))*64 + (row))*36) + (col))

// ---- split weights: W2S[pi][p][i][q] (j=2q+p), W3S[pi][c][i][q] (j=c+3q) ----
__global__ __launch_bounds__(256) void kSplit(
    const float* __restrict__ W2, const float* __restrict__ W3,
    ushort* __restrict__ W2S, ushort* __restrict__ W3S)
{
    int id = blockIdx.x * 256 + threadIdx.x;
    if (id < 1048576) {
        int p = id >> 19, rem = id & 524287, i = rem >> 9, q = rem & 511;
        ushort h, m, l;
        split3(W2[i * 1024 + 2 * q + p], h, m, l);
        size_t base = (size_t)p * 524288 + (size_t)i * 512 + q;
        W2S[base] = h; W2S[base + 1048576] = m; W2S[base + 2097152] = l;
    } else {
        int id2 = id - 1048576;
        if (id2 >= 1056768) return;
        int c = id2 / 352256, rem = id2 % 352256, i = rem / 344, q = rem % 344;
        int j = c + 3 * q;
        float w = (j < 1024) ? W3[i * 1024 + j] : 0.f;
        ushort h, m, l;
        split3(w, h, m, l);
        W3S[id2] = h; W3S[id2 + 1056768] = m; W3S[id2 + 2113536] = l;
    }
}

// ---- transpose input -> xT[784][1024] ----
__global__ __launch_bounds__(256) void kPrep(const float* __restrict__ input,
                                             float* __restrict__ xT)
{
    __shared__ float Ls[64][65];
    int bx = blockIdx.x, tid = threadIdx.x;
    int wt = bx >> 4, nt = bx & 15;
    int w0 = wt * 64, n0 = nt * 64;
#pragma unroll
    for (int j = 0; j < 16; ++j) {
        int flat = tid + 256 * j;
        int a = flat >> 6, c = flat & 63;
        Ls[a][c] = (w0 + c < 784) ? input[(size_t)(n0 + a) * 784 + w0 + c] : 0.f;
    }
    __syncthreads();
#pragma unroll
    for (int j = 0; j < 16; ++j) {
        int flat = tid + 256 * j;
        int ii = flat >> 6, nn = flat & 63;
        if (w0 + ii < 784) xT[(size_t)(w0 + ii) * 1024 + n0 + nn] = Ls[nn][ii];
    }
}

// ---- layer-1: phase A (t<12, varying window) + phase B (t>=12, constant window) ----
__global__ __launch_bounds__(256) void kL1(
    const float* __restrict__ xT, const float* __restrict__ W1,
    const float* __restrict__ b1,
    unsigned long long* __restrict__ s1bits, float* __restrict__ ss1)
{
    int tid = threadIdx.x;
    int waveId = (blockIdx.x << 2) + (tid >> 6);   // 0..4095
    int lane = tid & 63;
    int rowg = waveId >> 4;                        // 0..255
    int nblk = waveId & 15;
    int i0 = rowg << 2;
    int n = (nblk << 6) + lane;
    float w[4][8], bb[4], mem[4], cnt[4];
#pragma unroll
    for (int r = 0; r < 4; ++r) {
#pragma unroll
        for (int e = 0; e < 8; ++e) w[r][e] = W1[(i0 + r) * 8 + e];
        bb[r] = b1[i0 + r]; mem[r] = 0.f; cnt[r] = 0.f;
    }
    float x[8], xn[8];
#pragma unroll
    for (int e = 0; e < 8; ++e) x[e] = xT[(size_t)e * 1024 + n];
    for (int t = 0; t < 12; ++t) {
        int st1 = ((t + 1) * 8 < TTL - 8) ? (t + 1) * 8 : (784 - 8);
#pragma unroll
        for (int e = 0; e < 8; ++e) xn[e] = xT[(size_t)(st1 + e) * 1024 + n];
#pragma unroll
        for (int r = 0; r < 4; ++r) {
            if (((t ^ (i0 + r)) & 1) == 0) {       // parity rule exact for cycle 2 (98 even)
                float d = bb[r];
#pragma unroll
                for (int e = 0; e < 8; ++e) d += w[r][e] * x[e];
                float m = mem[r] * 0.5f + d;       // prev spike provably 0 at active steps
                mem[r] = m;
                bool sp = m > 0.5f;
                unsigned long long bm = __ballot(sp);
                if (lane == 0) s1bits[(size_t)(t * 512 + ((i0 + r) >> 1)) * 16 + nblk] = bm;
                if (sp) cnt[r] += 1.f;
            }
        }
#pragma unroll
        for (int e = 0; e < 8; ++e) x[e] = xn[e];
    }
    float dd[4];
#pragma unroll
    for (int r = 0; r < 4; ++r) {
        float d = bb[r];
#pragma unroll
        for (int e = 0; e < 8; ++e) d += w[r][e] * x[e];
        dd[r] = d;
    }
#pragma unroll 1
    for (int t = 12; t < TTL; t += 2) {            // t even: rows 0,2 ; t+1: rows 1,3
#pragma unroll
        for (int h = 0; h < 2; ++h) {
#pragma unroll
            for (int rr = 0; rr < 2; ++rr) {
                int r = h + rr * 2;
                float m = mem[r] * 0.5f + dd[r];
                mem[r] = m;
                bool sp = m > 0.5f;
                unsigned long long bm = __ballot(sp);
                if (lane == 0) s1bits[(size_t)((t + h) * 512 + ((i0 + r) >> 1)) * 16 + nblk] = bm;
                if (sp) cnt[r] += 1.f;
            }
        }
    }
#pragma unroll
    for (int r = 0; r < 4; ++r) ss1[(size_t)(i0 + r) * 1024 + n] = cnt[r];
}

// ---- per-t tables via prefix scan: u=(t-i) mod 98 (98%3,4 != 0 -> table, not residue) ----
__global__ __launch_bounds__(256) void kTab2(
    int* __restrict__ idx2, int* __restrict__ idx3, int* __restrict__ cq3)
{
    __shared__ int f2[256], f3[256];
    __shared__ int sidx2[384], sidx3[320];
    int t = blockIdx.x, tid = threadIdx.x;
    int a2[4], a3[4];
    int l2 = 0, l3 = 0;
#pragma unroll
    for (int e = 0; e < 4; ++e) {
        int i = tid * 4 + e;
        int u = (t - i) % TTL; if (u < 0) u += TTL;
        a2[e] = (u % 3 == 0); a3[e] = (u % 4 == 0);
        l2 += a2[e]; l3 += a3[e];
    }
    f2[tid] = l2; f3[tid] = l3;
    __syncthreads();
    for (int s = 1; s < 256; s <<= 1) {
        int v2 = (tid >= s) ? f2[tid - s] : 0;
        int v3 = (tid >= s) ? f3[tid - s] : 0;
        __syncthreads();
        f2[tid] += v2; f3[tid] += v3;
        __syncthreads();
    }
    int o2 = f2[tid] - l2, o3 = f3[tid] - l3;
    int c2 = f2[255], c3 = f3[255];
#pragma unroll
    for (int e = 0; e < 4; ++e) {
        int i = tid * 4 + e;
        if (a2[e]) { sidx2[o2] = i; ++o2; }
        if (a3[e]) { sidx3[o3] = i; ++o3; }
    }
    __syncthreads();
    for (int k = tid; k < 384; k += 256) idx2[t * 384 + k] = (k < c2) ? sidx2[k] : -1;
    for (int k = tid; k < 320; k += 256) idx3[t * 320 + k] = (k < c3) ? sidx3[k] : -1;
    for (int k = tid; k < 352; k += 256) {
        int j = (k < c2) ? sidx2[k] : 0;
        cq3[t * 352 + k] = (j % 3) * 352256 + j / 3;
    }
}

// ---- closed-form per-row activation lists ----
template<int C, int NACT>
__global__ __launch_bounds__(256) void kListCF(int* __restrict__ list)
{
    int flat = blockIdx.x * 256 + threadIdx.x;      // row*NACT + s
    if (flat >= 1024 * NACT) return;
    int i = flat / NACT, s = flat % NACT;
    int ri = i % 98;
    int k0 = (98 - ri + C - 1) / C;                 // first wrapped k
    int kw = NACT - k0; if (kw < 0) kw = 0;
    int t = (s < kw) ? (ri + (k0 + s) * C - 98) : (ri + (s - kw) * C);
    int rk = 0;
    int r = t;
#pragma unroll
    for (int k = 0; k < NACT; ++k) {
        rk += (r < i) ? (i - r + 97) / 98 : 0;      // count of i'<i with i'≡r (mod 98)
        r -= C; if (r < 0) r += 98;
    }
    list[i * NACT + s] = (t << 10) | rk;
}

// ---- bit-matrix transpose (layer-1, full range): [t][k][nw] -> [t][kw][n] ----
template<int K>
__global__ __launch_bounds__(256) void kXb(const unsigned* __restrict__ in,
                                           unsigned* __restrict__ out, int t0)
{
    constexpr int Kw = K / 32;
    __shared__ unsigned L[1024];
    int bx = blockIdx.x, tid = threadIdx.x;
    int tt = t0 + bx / Kw, kw = bx % Kw;
    const unsigned* ip = in + ((size_t)tt * K + kw * 32) * 32;
#pragma unroll
    for (int g = 0; g < 4; ++g) L[g * 256 + tid] = ip[g * 256 + tid];
    __syncthreads();
    unsigned* op = out + ((size_t)tt * Kw + kw) * 1024;
#pragma unroll
    for (int g = 0; g < 4; ++g) {
        int n = g * 256 + tid;
        int w = n >> 5, b = n & 31;
        unsigned acc = 0;
#pragma unroll
        for (int k = 0; k < 32; ++k) acc |= ((L[k * 32 + w] >> b) & 1u) << k;
        op[n] = acc;
    }
}

// ---- fused per-chunk body: layer-2 bit transpose (11 blocks/t) + layer-3 A-gather (55/t) ----
__device__ __forceinline__ void xbg3a_body(
    int bx, int tid, unsigned* L,
    const unsigned* __restrict__ s2b, unsigned* __restrict__ s2bT,
    const ushort* __restrict__ Ws, const int* __restrict__ idx3,
    const int* __restrict__ cq3, ushort* __restrict__ AW3, int t0)
{
    int tloc = bx / 66, r66 = bx % 66;
    int t = t0 + tloc;
    if (r66 < 11) {
        int kw = r66;
        const unsigned* ip = s2b + ((size_t)t * 352 + kw * 32) * 32;
#pragma unroll
        for (int g = 0; g < 4; ++g) L[g * 256 + tid] = ip[g * 256 + tid];
        __syncthreads();
        unsigned* op = s2bT + ((size_t)t * 11 + kw) * 1024;
#pragma unroll
        for (int g = 0; g < 4; ++g) {
            int n = g * 256 + tid;
            int w = n >> 5, b = n & 31;
            unsigned acc = 0;
#pragma unroll
            for (int k = 0; k < 32; ++k) acc |= ((L[k * 32 + w] >> b) & 1u) << k;
            op[n] = acc;
        }
    } else {
        int blk = r66 - 11;
        int flat = blk * 256 + tid;      // 0..14079 = 320 rows * 44 k-groups
        int r = flat / 44, kg = flat % 44;
        int k0 = kg * 8;
        int v = idx3[t * 320 + r];
        int i = v < 0 ? 0 : v;           // pad rows: garbage, never read back
        const int* cq = cq3 + t * 352 + k0;
        int c0 = cq[0], c1 = cq[1], c2 = cq[2], c3 = cq[3],
            c4 = cq[4], c5 = cq[5], c6 = cq[6], c7 = cq[7];
        size_t ia = (size_t)i * 344;
#pragma unroll
        for (int pi = 0; pi < 3; ++pi) {
            const ushort* wp = Ws + (size_t)pi * 1056768 + ia;
            union { ushort us[8]; ul2 v2; } o;
            o.us[0] = wp[c0]; o.us[1] = wp[c1]; o.us[2] = wp[c2]; o.us[3] = wp[c3];
            o.us[4] = wp[c4]; o.us[5] = wp[c5]; o.us[6] = wp[c6]; o.us[7] = wp[c7];
            *(ul2*)(AW3 + ((size_t)tloc * 3 + pi) * 112640 + (size_t)r * 352 + k0) = o.v2;
        }
    }
}

// ==================== GEMM bodies (64x64 wave tiles, LDS dbuf, proven round-7/11 config) ====================

__device__ __forceinline__ void gm2_body(
    int bx, int tid, ushort* AsR,
    const ushort* __restrict__ Ws, const unsigned* __restrict__ s1bT,
    const int* __restrict__ idx2, float* __restrict__ drive, int t0)
{
    int tloc = bx / 24, rem = bx % 24;
    int mt = rem >> 2, nt4 = rem & 3;
    int t = t0 + tloc;
    int p = t & 1;
    int r0 = mt * 64, n0 = nt4 * 256;
    int ar = tid >> 2, ak8 = (tid & 3) * 8;
    int vR = idx2[t * 384 + r0 + ar];
    const ushort* Wrow = Ws + (size_t)p * 524288 + (size_t)(vR < 0 ? 0 : vR) * 512 + ak8;
    int wv = tid >> 6, lane = tid & 63;
    int mrow = lane & 31, kh8 = (lane >> 5) * 8;
    int nb = n0 + wv * 64 + mrow;
    f16v acc[2][2];
#pragma unroll
    for (int a = 0; a < 2; ++a)
#pragma unroll
        for (int b = 0; b < 2; ++b) acc[a][b] = (f16v)(0.f);

    ul2 c0r[3];
#pragma unroll
    for (int pi = 0; pi < 3; ++pi) c0r[pi] = *(const ul2*)(Wrow + (size_t)pi * 1048576);
#pragma unroll
    for (int pi = 0; pi < 3; ++pi) ldsWR(&AsR[ASOFF(0, pi, ar, ak8)], c0r[pi]);
    ul2 nxt[3];
#pragma unroll
    for (int pi = 0; pi < 3; ++pi) nxt[pi] = *(const ul2*)(Wrow + (size_t)pi * 1048576 + 32);
    unsigned w4c[2];
#pragma unroll
    for (int jj = 0; jj < 2; ++jj) w4c[jj] = s1bT[(size_t)t * 16 * 1024 + nb + jj * 32];
    __syncthreads();

    int cur = 0;
    for (int kc = 0; kc < 512; kc += 32) {
        if (kc + 32 < 512) {
#pragma unroll
            for (int pi = 0; pi < 3; ++pi) ldsWR(&AsR[ASOFF(cur ^ 1, pi, ar, ak8)], nxt[pi]);
        }
        unsigned w4n[2];
        if (kc + 32 < 512) {
#pragma unroll
            for (int jj = 0; jj < 2; ++jj)
                w4n[jj] = s1bT[((size_t)t * 16 + ((kc + 32) >> 5)) * 1024 + nb + jj * 32];
        }
        ul2 n2[3];
        if (kc + 64 < 512) {
#pragma unroll
            for (int pi = 0; pi < 3; ++pi)
                n2[pi] = *(const ul2*)(Wrow + (size_t)pi * 1048576 + kc + 64);
        }
#pragma unroll
        for (int s2 = 0; s2 < 2; ++s2) {
            int kcol = s2 * 16 + kh8;
            short8 bf[2];
#pragma unroll
            for (int jj = 0; jj < 2; ++jj) bf[jj] = expand8((w4c[jj] >> kcol) & 0xFFu);
#pragma unroll
            for (int wr2 = 0; wr2 < 2; ++wr2) {
                short8 af0 = ldsAF(&AsR[ASOFF(cur, 0, wr2 * 32 + mrow, kcol)]);
                short8 af1 = ldsAF(&AsR[ASOFF(cur, 1, wr2 * 32 + mrow, kcol)]);
                short8 af2 = ldsAF(&AsR[ASOFF(cur, 2, wr2 * 32 + mrow, kcol)]);
#pragma unroll
                for (int jj = 0; jj < 2; ++jj) {
                    acc[wr2][jj] = __builtin_amdgcn_mfma_f32_32x32x16_bf16(af2, bf[jj], acc[wr2][jj], 0, 0, 0);
                    acc[wr2][jj] = __builtin_amdgcn_mfma_f32_32x32x16_bf16(af1, bf[jj], acc[wr2][jj], 0, 0, 0);
                    acc[wr2][jj] = __builtin_amdgcn_mfma_f32_32x32x16_bf16(af0, bf[jj], acc[wr2][jj], 0, 0, 0);
                }
            }
        }
        __syncthreads();
        cur ^= 1;
        nxt[0] = n2[0]; nxt[1] = n2[1]; nxt[2] = n2[2];
        w4c[0] = w4n[0]; w4c[1] = w4n[1];
    }
#pragma unroll
    for (int wr2 = 0; wr2 < 2; ++wr2)
#pragma unroll
        for (int jj = 0; jj < 2; ++jj)
#pragma unroll
            for (int reg = 0; reg < 16; ++reg) {
                int rowl = r0 + wr2 * 32 + (reg & 3) + 8 * (reg >> 2) + 4 * (lane >> 5);
                drive[((size_t)tloc * 384 + rowl) * 1024 + nb + jj * 32] = acc[wr2][jj][reg];
            }
}

__device__ __forceinline__ void gm3_body(
    int bx, int tid, ushort* AsR,
    const ushort* __restrict__ AW3, const unsigned* __restrict__ s2bT,
    float* __restrict__ drive, int t0)
{
    int tloc = bx / 20, rem = bx % 20;
    int mt = rem >> 2, nt4 = rem & 3;
    int t = t0 + tloc;
    int r0 = mt * 64, n0 = nt4 * 256;
    int ar = tid >> 2, ak8 = (tid & 3) * 8;
    const ushort* Ab = AW3 + (size_t)tloc * 337920 + (size_t)(r0 + ar) * 352 + ak8;
    int wv = tid >> 6, lane = tid & 63;
    int mrow = lane & 31, kh8 = (lane >> 5) * 8;
    int nb = n0 + wv * 64 + mrow;
    f16v acc[2][2];
#pragma unroll
    for (int a = 0; a < 2; ++a)
#pragma unroll
        for (int b = 0; b < 2; ++b) acc[a][b] = (f16v)(0.f);

    ul2 c0r[3];
#pragma unroll
    for (int pi = 0; pi < 3; ++pi) c0r[pi] = *(const ul2*)(Ab + (size_t)pi * 112640);
#pragma unroll
    for (int pi = 0; pi < 3; ++pi) ldsWR(&AsR[ASOFF(0, pi, ar, ak8)], c0r[pi]);
    ul2 nxt[3];
#pragma unroll
    for (int pi = 0; pi < 3; ++pi) nxt[pi] = *(const ul2*)(Ab + (size_t)pi * 112640 + 32);
    unsigned w4c[2];
#pragma unroll
    for (int jj = 0; jj < 2; ++jj) w4c[jj] = s2bT[(size_t)t * 11 * 1024 + nb + jj * 32];
    __syncthreads();

    int cur = 0;
    for (int kc = 0; kc < 352; kc += 32) {
        if (kc + 32 < 352) {
#pragma unroll
            for (int pi = 0; pi < 3; ++pi) ldsWR(&AsR[ASOFF(cur ^ 1, pi, ar, ak8)], nxt[pi]);
        }
        unsigned w4n[2];
        if (kc + 32 < 352) {
#pragma unroll
            for (int jj = 0; jj < 2; ++jj)
                w4n[jj] = s2bT[((size_t)t * 11 + ((kc + 32) >> 5)) * 1024 + nb + jj * 32];
        }
        ul2 n2[3];
        if (kc + 64 < 352) {
#pragma unroll
            for (int pi = 0; pi < 3; ++pi)
                n2[pi] = *(const ul2*)(Ab + (size_t)pi * 112640 + kc + 64);
        }
#pragma unroll
        for (int s2 = 0; s2 < 2; ++s2) {
            int kcol = s2 * 16 + kh8;
            short8 bf[2];
#pragma unroll
            for (int jj = 0; jj < 2; ++jj) bf[jj] = expand8((w4c[jj] >> kcol) & 0xFFu);
#pragma unroll
            for (int wr2 = 0; wr2 < 2; ++wr2) {
                short8 af0 = ldsAF(&AsR[ASOFF(cur, 0, wr2 * 32 + mrow, kcol)]);
                short8 af1 = ldsAF(&AsR[ASOFF(cur, 1, wr2 * 32 + mrow, kcol)]);
                short8 af2 = ldsAF(&AsR[ASOFF(cur, 2, wr2 * 32 + mrow, kcol)]);
#pragma unroll
                for (int jj = 0; jj < 2; ++jj) {
                    acc[wr2][jj] = __builtin_amdgcn_mfma_f32_32x32x16_bf16(af2, bf[jj], acc[wr2][jj], 0, 0, 0);
                    acc[wr2][jj] = __builtin_amdgcn_mfma_f32_32x32x16_bf16(af1, bf[jj], acc[wr2][jj], 0, 0, 0);
                    acc[wr2][jj] = __builtin_amdgcn_mfma_f32_32x32x16_bf16(af0, bf[jj], acc[wr2][jj], 0, 0, 0);
                }
            }
        }
        __syncthreads();
        cur ^= 1;
        nxt[0] = n2[0]; nxt[1] = n2[1]; nxt[2] = n2[2];
        w4c[0] = w4n[0]; w4c[1] = w4n[1];
    }
#pragma unroll
    for (int wr2 = 0; wr2 < 2; ++wr2)
#pragma unroll
        for (int jj = 0; jj < 2; ++jj)
#pragma unroll
            for (int reg = 0; reg < 16; ++reg) {
                int rowl = r0 + wr2 * 32 + (reg & 3) + 8 * (reg >> 2) + 4 * (lane >> 5);
                drive[((size_t)tloc * 320 + rowl) * 1024 + nb + jj * 32] = acc[wr2][jj][reg];
            }
}

// ---- chunk recurrence body: one wave per (row, 64-col block), depth-2 drive prefetch ----
template<int MP, int KBP, bool BITS, int NACT>
__device__ __forceinline__ void rk_body(
    int bx, int tid,
    const float* __restrict__ drive, const float* __restrict__ bias,
    const int* __restrict__ list,
    float* __restrict__ mG, float* __restrict__ ssG,
    unsigned long long* __restrict__ bitsOut, int t0, int nt)
{
    int row = bx >> 2;                               // 0..1023
    int wv  = ((bx & 3) << 2) + (tid >> 6);          // nblk 0..15
    int lane = tid & 63;
    int n = (wv << 6) + lane;
    size_t idx = (size_t)row * 1024 + n;
    float mv = mG[idx];
    float cnt = 0.f;
    float bv = bias[row];
    const int* lp = list + row * NACT;               // wave-uniform -> scalar loads
    int t1 = t0 + nt;
    int s0 = 0;
    while (s0 < NACT && (lp[s0] >> 10) < t0) ++s0;
    int s1 = s0;
    while (s1 < NACT && (lp[s1] >> 10) < t1) ++s1;
    if (s0 < s1) {
        int v0 = lp[s0];
        float d0 = drive[((size_t)((v0 >> 10) - t0) * MP + (v0 & 1023)) * 1024 + n];
        int v1 = 0; float d1 = 0.f;
        if (s0 + 1 < s1) {
            v1 = lp[s0 + 1];
            d1 = drive[((size_t)((v1 >> 10) - t0) * MP + (v1 & 1023)) * 1024 + n];
        }
        for (int s = s0; s < s1; ++s) {
            int vc = v0;
            float dcur = d0;
            v0 = v1; d0 = d1;
            if (s + 2 < s1) {
                v1 = lp[s + 2];
                d1 = drive[((size_t)((v1 >> 10) - t0) * MP + (v1 & 1023)) * 1024 + n];
            }
            float d = dcur + bv;
            float m = mv * 0.5f + d;
            mv = m;
            bool sp = m > 0.5f;
            if (BITS) {
                unsigned long long bm = __ballot(sp);
                if (lane == 0) bitsOut[((size_t)(vc >> 10) * KBP + (vc & 1023)) * 16 + wv] = bm;
            }
            cnt += sp ? 1.f : 0.f;
        }
    }
    mG[idx] = mv;
    ssG[idx] += cnt;
}

// ---- standalone wrappers for the pipeline prologue ----
__global__ __launch_bounds__(256) void kGM2K(
    const ushort* __restrict__ Ws, const unsigned* __restrict__ s1bT,
    const int* __restrict__ idx2, float* __restrict__ drive, int t0)
{
    __shared__ ushort AsR[2 * 3 * 64 * 36];
    gm2_body(blockIdx.x, threadIdx.x, AsR, Ws, s1bT, idx2, drive, t0);
}

template<int MP, int KBP, bool BITS, int NACT>
__global__ __launch_bounds__(256) void kRK(
    const float* __restrict__ drive, const float* __restrict__ bias,
    const int* __restrict__ list,
    float* __restrict__ mG, float* __restrict__ ssG,
    unsigned long long* __restrict__ bitsOut, int t0, int nt)
{
    rk_body<MP, KBP, BITS, NACT>(blockIdx.x, threadIdx.x, drive, bias, list,
                                 mG, ssG, bitsOut, t0, nt);
}

// ==================== Heterogeneous fused dispatches (small-grid residency mixing) ====================
// F1(i): GM3(i) [n3b blocks, MFMA-bound] + RK2(i+1) [4096 blocks, memory-bound].
// GM3 grid (<= 500) undershoots residency capacity (~5 blk/CU * 256) -> RK2 blocks
// co-resident immediately: MFMA pipe and VMEM pipe overlap (m114).
__global__ __launch_bounds__(256) void kF1(
    const ushort* __restrict__ AW3, const unsigned* __restrict__ s2bT,
    float* __restrict__ drv3, int t0_3, int n3b,
    const float* __restrict__ drv2, const float* __restrict__ b2,
    const int* __restrict__ list2, float* __restrict__ m2, float* __restrict__ ss2,
    unsigned long long* __restrict__ s2bits, int t0_2, int nt2)
{
    __shared__ ushort AsR[2 * 3 * 64 * 36];
    int bx = blockIdx.x;
    if (bx < n3b) gm3_body(bx, threadIdx.x, AsR, AW3, s2bT, drv3, t0_3);
    else rk_body<384, 352, true, 33>(bx - n3b, threadIdx.x, drv2, b2, list2,
                                     m2, ss2, s2bits, t0_2, nt2);
}

// F2(i): GM2(i+2) [n2b] + RK3(i) [nrk3] + XbG3A(i+1) [nxb].
__global__ __launch_bounds__(256) void kF2(
    const ushort* __restrict__ W2S, const unsigned* __restrict__ s1bT,
    const int* __restrict__ idx2, float* __restrict__ drv2, int t0_2, int n2b,
    const float* __restrict__ drv3, const float* __restrict__ b3,
    const int* __restrict__ list3, float* __restrict__ m3, float* __restrict__ ss3,
    int t0_3, int nt3, int nrk3,
    const unsigned* __restrict__ s2b, unsigned* __restrict__ s2bT,
    const ushort* __restrict__ W3S, const int* __restrict__ idx3,
    const int* __restrict__ cq3, ushort* __restrict__ AW3, int t0_x)
{
    __shared__ ushort AsR[2 * 3 * 64 * 36];
    int bx = blockIdx.x;
    if (bx < n2b) { gm2_body(bx, threadIdx.x, AsR, W2S, s1bT, idx2, drv2, t0_2); return; }
    bx -= n2b;
    if (bx < nrk3) { rk_body<320, 0, false, 25>(bx, threadIdx.x, drv3, b3, list3,
                                                m3, ss3, nullptr, t0_3, nt3); return; }
    bx -= nrk3;
    xbg3a_body(bx, threadIdx.x, (unsigned*)AsR, s2b, s2bT, W3S, idx3, cq3, AW3, t0_x);
}

// ---- tail: ss transposes + fr; W4 GEMV partials into osum ----
__global__ __launch_bounds__(256) void kTail(
    const float* __restrict__ ssBase, const float* __restrict__ W4,
    float* __restrict__ osum, float* __restrict__ out, float* __restrict__ fr)
{
    int bx = blockIdx.x, tid = threadIdx.x;
    if (bx < 768) {
        __shared__ float Ls[64][65];
        __shared__ float red[4];
        int l = bx >> 8;
        int tile = bx & 255;
        int i0 = (tile >> 4) * 64, n0 = (tile & 15) * 64;
        const float* ss = ssBase + (size_t)l * MM;
        float* o = out + 10240 + (size_t)l * MM;
        float sum = 0.f;
#pragma unroll
        for (int j = 0; j < 16; ++j) {
            int flat = tid + 256 * j;
            int a = flat >> 6, c = flat & 63;
            float v = ss[(size_t)(i0 + a) * 1024 + n0 + c];
            Ls[a][c] = v;
            sum += v;
        }
        __syncthreads();
        for (int off = 32; off > 0; off >>= 1) sum += __shfl_down(sum, off, 64);
        if ((tid & 63) == 0) red[tid >> 6] = sum;
        __syncthreads();
        if (tid == 0) {
            float s = red[0] + red[1] + red[2] + red[3];
            atomicAdd(&fr[l], s * (1.0f / (1024.0f * 1024.0f * 98.0f)));
        }
#pragma unroll
        for (int j = 0; j < 16; ++j) {
            int flat = tid + 256 * j;
            int nn = flat >> 6, ii = flat & 63;
            o[(size_t)(n0 + nn) * 1024 + i0 + ii] = Ls[ii][nn] * (1.0f / 98.0f);
        }
    } else {
        int b = bx - 768;
        int ks = b >> 4, nt = b & 15;
        int n = nt * 64 + (tid & 63);
        int og = tid >> 6;
        const float* ss3 = ssBase + (size_t)2 * MM;
        float a0 = 0.f, a1 = 0.f, a2 = 0.f;
        int k0 = ks * 256;
        for (int k = k0; k < k0 + 256; ++k) {
            float v = ss3[(size_t)k * 1024 + n];
            a0 += v * W4[og * 1024 + k];
            a1 += v * W4[(og + 4) * 1024 + k];
            if (og < 2) a2 += v * W4[(og + 8) * 1024 + k];
        }
        atomicAdd(&osum[n * OUTD + og], a0);
        atomicAdd(&osum[n * OUTD + og + 4], a1);
        if (og < 2) atomicAdd(&osum[n * OUTD + og + 8], a2);
    }
}

__global__ void kOut(const float* __restrict__ osum, const float* __restrict__ b4,
                     float* __restrict__ out)
{
    int idx = blockIdx.x * 256 + threadIdx.x;
    if (idx < 1024 * OUTD) out[idx] = osum[idx] * (1.0f / 98.0f) + b4[idx % OUTD];
}

extern "C" void kernel_launch(void* const* d_in, const int* in_sizes, int n_in,
                              void* d_out, int out_size, void* d_ws, size_t ws_size,
                              hipStream_t stream)
{
    const float* input = (const float*)d_in[0];
    const float* W1    = (const float*)d_in[1];
    const float* b1    = (const float*)d_in[2];
    const float* W2    = (const float*)d_in[3];
    const float* b2    = (const float*)d_in[4];
    const float* W3    = (const float*)d_in[5];
    const float* b3    = (const float*)d_in[6];
    const float* W4    = (const float*)d_in[7];
    const float* b4    = (const float*)d_in[8];

    float* ws = (float*)d_ws;
    float* ss1  = ws;
    float* ss2  = ws + MM;
    float* ss3  = ws + 2 * MM;
    float* m2   = ws + 3 * MM;
    float* m3   = ws + 4 * MM;
    float* osum = ws + OFF_OSUM;
    float* xT   = ws + OFF_XT;
    int*   tabs = (int*)(ws + OFF_XT);   // reuses xT region after kL1
    int* idx2  = tabs + TAB_IDX2;
    int* idx3  = tabs + TAB_IDX3;
    int* cq3   = tabs + TAB_CQ3;
    int* list2 = tabs + TAB_L2;
    int* list3 = tabs + TAB_L3;
    unsigned int* s1b  = (unsigned int*)(ws + OFF_S1B);
    unsigned int* s2b  = (unsigned int*)(ws + OFF_S2B);
    unsigned int* s1bT = (unsigned int*)(ws + OFF_S1BT);
    unsigned int* s2bT = (unsigned int*)(ws + OFF_S2BT);
    ushort* W2S = (ushort*)(ws + OFF_W2S);
    ushort* W3S = (ushort*)(ws + OFF_W3S);
    float* out  = (float*)d_out;

    // chunk size: SMALL on purpose -- grids must undershoot residency so the
    // heterogeneous fused dispatches actually co-schedule (round-11 lesson).
    size_t availF = ws_size / sizeof(float);
    constexpr size_t PER_T = AW3_PER_T + 384 * 1024 + 320 * 1024;   // 889,856 floats
    int tc = 10;
    const int cands[3] = {25, 14, 10};
    for (int ci = 0; ci < 3; ++ci) {
        if (FIX_END + (size_t)cands[ci] * PER_T <= availF) { tc = cands[ci]; break; }
    }
    ushort* AW3 = (ushort*)(ws + FIX_END);
    float* drv2 = ws + FIX_END + (size_t)tc * AW3_PER_T;
    float* drv3 = drv2 + (size_t)tc * 384 * 1024;

    hipMemsetAsync(ws, 0, (5 * MM + 10240) * sizeof(float), stream);   // ss, m2, m3, osum
    hipMemsetAsync(s2b, 0, 1103872 * sizeof(unsigned int), stream);    // layer-2 bits (pad ranks)
    hipMemsetAsync(out + 3155968, 0, 3 * sizeof(float), stream);       // fr

    kSplit<<<8224, 256, 0, stream>>>(W2, W3, W2S, W3S);
    kPrep<<<208, 256, 0, stream>>>(input, xT);
    kL1<<<1024, 256, 0, stream>>>(xT, W1, b1, (unsigned long long*)s1b, ss1);
    kTab2<<<98, 256, 0, stream>>>(idx2, idx3, cq3);                    // after kL1: reuses xT mem
    kListCF<3, 33><<<132, 256, 0, stream>>>(list2);
    kListCF<4, 25><<<100, 256, 0, stream>>>(list3);
    kXb<512><<<1568, 256, 0, stream>>>(s1b, s1bT, 0);

    int nc = (TTL + tc - 1) / tc;
    auto ntOf = [&](int c) { int t0c = c * tc; return (TTL - t0c < tc) ? (TTL - t0c) : tc; };

    // prologue: GM2(0); RK2(0); P3 = GM2(1) + XbG3A(0)
    kGM2K<<<ntOf(0) * 24, 256, 0, stream>>>(W2S, s1bT, idx2, drv2, 0);
    kRK<384, 352, true, 33><<<4096, 256, 0, stream>>>(drv2, b2, list2, m2, ss2,
                                                      (unsigned long long*)s2b, 0, ntOf(0));
    {
        int n2b = (nc > 1) ? ntOf(1) * 24 : 0;
        int nxb = ntOf(0) * 66;
        kF2<<<n2b + nxb, 256, 0, stream>>>(W2S, s1bT, idx2, drv2, tc, n2b,
                                           drv3, b3, list3, m3, ss3, 0, 0, 0,
                                           s2b, s2bT, W3S, idx3, cq3, AW3, 0);
    }
    // steady state: F1(i) = GM3(i) + RK2(i+1);  F2(i) = GM2(i+2) + RK3(i) + XbG3A(i+1)
    for (int i = 0; i < nc; ++i) {
        int n3b = ntOf(i) * 20;
        int nt2 = (i + 1 < nc) ? ntOf(i + 1) : 0;
        kF1<<<n3b + (nt2 ? 4096 : 0), 256, 0, stream>>>(
            AW3, s2bT, drv3, i * tc, n3b,
            drv2, b2, list2, m2, ss2, (unsigned long long*)s2b, (i + 1) * tc, nt2);
        int n2b = (i + 2 < nc) ? ntOf(i + 2) * 24 : 0;
        int nxb = (i + 1 < nc) ? ntOf(i + 1) * 66 : 0;
        kF2<<<n2b + 4096 + nxb, 256, 0, stream>>>(
            W2S, s1bT, idx2, drv2, (i + 2) * tc, n2b,
            drv3, b3, list3, m3, ss3, i * tc, ntOf(i), 4096,
            s2b, s2bT, W3S, idx3, cq3, AW3, (i + 1) * tc);
    }

    kTail<<<832, 256, 0, stream>>>(ss1, W4, osum, out, out + 3155968);
    kOut<<<40, 256, 0, stream>>>(osum, b4, out);
}

// Round 14
// 517.464 us; speedup vs baseline: 1.3067x; 1.2072x over previous
//
#include <hip/hip_runtime.h>

#define TTL 98
#define OUTD 10

typedef float f16v __attribute__((ext_vector_type(16)));
typedef short short8 __attribute__((ext_vector_type(8)));
typedef unsigned long ul2 __attribute__((ext_vector_type(2)));
typedef unsigned short ushort;

constexpr size_t MM = 1048576;
constexpr size_t OFF_OSUM = 5 * MM;                  // 10,240
constexpr size_t OFF_XT   = OFF_OSUM + 10240;        // 802,816 (tables reuse after kL1)
constexpr size_t OFF_S1B  = OFF_XT + 802816;         // u32: 98*512*32
constexpr size_t OFF_S2B  = OFF_S1B + 1605632;       // u32: 98*352*32
constexpr size_t OFF_S1BT = OFF_S2B + 1103872;       // u32: 98*16*1024 (bit-transposed L1)
constexpr size_t OFF_S2BT = OFF_S1BT + 1605632;      // u32: 98*11*1024 (bit-transposed L2)
constexpr size_t OFF_W2S  = OFF_S2BT + 1103872;      // bf16 3*2*1024*512
constexpr size_t OFF_W3S  = OFF_W2S + 1572864;       // bf16 3*3*1024*344
constexpr size_t FIX_END  = OFF_W3S + 1585152;       // 14,632,960 floats (58.5 MB)

constexpr size_t TAB_IDX2 = 0;        // 98*384
constexpr size_t TAB_IDX3 = 37632;    // 98*320
constexpr size_t TAB_CQ3  = 269696;   // 98*352
constexpr size_t TAB_L2   = 304192;   // 1024*33 packed (t<<10|rk), exactly 33 per row
constexpr size_t TAB_L3   = 337984;   // 1024*25 packed, exactly 25 per row

// AW3 per-t footprint: 3 * 320 * 352 ushort = 337,920 ushort = 168,960 floats (FULL size).
constexpr size_t AW3_PER_T = 168960;

// ---- exact 3-way bf16 split by truncation: hi+mid+lo == w bit-exactly ----
__device__ inline void split3(float w, ushort& h, ushort& m, ushort& l) {
    unsigned u = __float_as_uint(w);
    h = (ushort)(u >> 16);
    float r1 = w - __uint_as_float(u & 0xFFFF0000u);
    unsigned u1 = __float_as_uint(r1);
    m = (ushort)(u1 >> 16);
    float r2 = r1 - __uint_as_float(u1 & 0xFFFF0000u);
    l = (ushort)(__float_as_uint(r2) >> 16);
}

// ---- 8 spike bits -> short8 of bf16 {0,1} (element e = bit e) ----
__device__ inline short8 expand8(unsigned x) {
    union { unsigned u[4]; short8 v; } r;
#pragma unroll
    for (int q = 0; q < 4; ++q) {
        unsigned b = x >> (2 * q);
        r.u[q] = ((b & 1u) * 0x3F80u) | ((b & 2u) ? 0x3F800000u : 0u);
    }
    return r.v;
}

// ---- LDS helpers: 72B-stride rows -> b64 pairs ----
__device__ inline short8 ldsAF(const ushort* base) {
    union { unsigned long u[2]; short8 s; } r;
    r.u[0] = *(const unsigned long*)(base);
    r.u[1] = *(const unsigned long*)(base + 4);
    return r.s;
}
__device__ inline void ldsWR(ushort* dst, ul2 v) {
    *(unsigned long*)(dst) = v[0];
    *(unsigned long*)(dst + 4) = v[1];
}
// As layout (raw): [cur][pi][row][col36]
#define ASOFF(cur, pi, row, col) (((((cur)*3 + (pi))*64 + (row))*36) + (col))

// ---- split weights: W2S[pi][p][i][q] (j=2q+p), W3S[pi][c][i][q] (j=c+3q) ----
__global__ __launch_bounds__(256) void kSplit(
    const float* __restrict__ W2, const float* __restrict__ W3,
    ushort* __restrict__ W2S, ushort* __restrict__ W3S)
{
    int id = blockIdx.x * 256 + threadIdx.x;
    if (id < 1048576) {
        int p = id >> 19, rem = id & 524287, i = rem >> 9, q = rem & 511;
        ushort h, m, l;
        split3(W2[i * 1024 + 2 * q + p], h, m, l);
        size_t base = (size_t)p * 524288 + (size_t)i * 512 + q;
        W2S[base] = h; W2S[base + 1048576] = m; W2S[base + 2097152] = l;
    } else {
        int id2 = id - 1048576;
        if (id2 >= 1056768) return;
        int c = id2 / 352256, rem = id2 % 352256, i = rem / 344, q = rem % 344;
        int j = c + 3 * q;
        float w = (j < 1024) ? W3[i * 1024 + j] : 0.f;
        ushort h, m, l;
        split3(w, h, m, l);
        W3S[id2] = h; W3S[id2 + 1056768] = m; W3S[id2 + 2113536] = l;
    }
}

// ---- transpose input -> xT[784][1024] ----
__global__ __launch_bounds__(256) void kPrep(const float* __restrict__ input,
                                             float* __restrict__ xT)
{
    __shared__ float Ls[64][65];
    int bx = blockIdx.x, tid = threadIdx.x;
    int wt = bx >> 4, nt = bx & 15;
    int w0 = wt * 64, n0 = nt * 64;
#pragma unroll
    for (int j = 0; j < 16; ++j) {
        int flat = tid + 256 * j;
        int a = flat >> 6, c = flat & 63;
        Ls[a][c] = (w0 + c < 784) ? input[(size_t)(n0 + a) * 784 + w0 + c] : 0.f;
    }
    __syncthreads();
#pragma unroll
    for (int j = 0; j < 16; ++j) {
        int flat = tid + 256 * j;
        int ii = flat >> 6, nn = flat & 63;
        if (w0 + ii < 784) xT[(size_t)(w0 + ii) * 1024 + n0 + nn] = Ls[nn][ii];
    }
}

// ---- layer-1: phase A (t<12, varying window) + phase B (t>=12, constant window) ----
__global__ __launch_bounds__(256) void kL1(
    const float* __restrict__ xT, const float* __restrict__ W1,
    const float* __restrict__ b1,
    unsigned long long* __restrict__ s1bits, float* __restrict__ ss1)
{
    int tid = threadIdx.x;
    int waveId = (blockIdx.x << 2) + (tid >> 6);   // 0..4095
    int lane = tid & 63;
    int rowg = waveId >> 4;                        // 0..255
    int nblk = waveId & 15;
    int i0 = rowg << 2;
    int n = (nblk << 6) + lane;
    float w[4][8], bb[4], mem[4], cnt[4];
#pragma unroll
    for (int r = 0; r < 4; ++r) {
#pragma unroll
        for (int e = 0; e < 8; ++e) w[r][e] = W1[(i0 + r) * 8 + e];
        bb[r] = b1[i0 + r]; mem[r] = 0.f; cnt[r] = 0.f;
    }
    float x[8], xn[8];
#pragma unroll
    for (int e = 0; e < 8; ++e) x[e] = xT[(size_t)e * 1024 + n];
    for (int t = 0; t < 12; ++t) {
        int st1 = ((t + 1) * 8 < TTL - 8) ? (t + 1) * 8 : (784 - 8);
#pragma unroll
        for (int e = 0; e < 8; ++e) xn[e] = xT[(size_t)(st1 + e) * 1024 + n];
#pragma unroll
        for (int r = 0; r < 4; ++r) {
            if (((t ^ (i0 + r)) & 1) == 0) {       // parity rule exact for cycle 2 (98 even)
                float d = bb[r];
#pragma unroll
                for (int e = 0; e < 8; ++e) d += w[r][e] * x[e];
                float m = mem[r] * 0.5f + d;       // prev spike provably 0 at active steps
                mem[r] = m;
                bool sp = m > 0.5f;
                unsigned long long bm = __ballot(sp);
                if (lane == 0) s1bits[(size_t)(t * 512 + ((i0 + r) >> 1)) * 16 + nblk] = bm;
                if (sp) cnt[r] += 1.f;
            }
        }
#pragma unroll
        for (int e = 0; e < 8; ++e) x[e] = xn[e];
    }
    float dd[4];
#pragma unroll
    for (int r = 0; r < 4; ++r) {
        float d = bb[r];
#pragma unroll
        for (int e = 0; e < 8; ++e) d += w[r][e] * x[e];
        dd[r] = d;
    }
#pragma unroll 1
    for (int t = 12; t < TTL; t += 2) {            // t even: rows 0,2 ; t+1: rows 1,3
#pragma unroll
        for (int h = 0; h < 2; ++h) {
#pragma unroll
            for (int rr = 0; rr < 2; ++rr) {
                int r = h + rr * 2;
                float m = mem[r] * 0.5f + dd[r];
                mem[r] = m;
                bool sp = m > 0.5f;
                unsigned long long bm = __ballot(sp);
                if (lane == 0) s1bits[(size_t)((t + h) * 512 + ((i0 + r) >> 1)) * 16 + nblk] = bm;
                if (sp) cnt[r] += 1.f;
            }
        }
    }
#pragma unroll
    for (int r = 0; r < 4; ++r) ss1[(size_t)(i0 + r) * 1024 + n] = cnt[r];
}

// ---- per-t tables via prefix scan: u=(t-i) mod 98 (98%3,4 != 0 -> table, not residue) ----
__global__ __launch_bounds__(256) void kTab2(
    int* __restrict__ idx2, int* __restrict__ idx3, int* __restrict__ cq3)
{
    __shared__ int f2[256], f3[256];
    __shared__ int sidx2[384], sidx3[320];
    int t = blockIdx.x, tid = threadIdx.x;
    int a2[4], a3[4];
    int l2 = 0, l3 = 0;
#pragma unroll
    for (int e = 0; e < 4; ++e) {
        int i = tid * 4 + e;
        int u = (t - i) % TTL; if (u < 0) u += TTL;
        a2[e] = (u % 3 == 0); a3[e] = (u % 4 == 0);
        l2 += a2[e]; l3 += a3[e];
    }
    f2[tid] = l2; f3[tid] = l3;
    __syncthreads();
    for (int s = 1; s < 256; s <<= 1) {
        int v2 = (tid >= s) ? f2[tid - s] : 0;
        int v3 = (tid >= s) ? f3[tid - s] : 0;
        __syncthreads();
        f2[tid] += v2; f3[tid] += v3;
        __syncthreads();
    }
    int o2 = f2[tid] - l2, o3 = f3[tid] - l3;
    int c2 = f2[255], c3 = f3[255];
#pragma unroll
    for (int e = 0; e < 4; ++e) {
        int i = tid * 4 + e;
        if (a2[e]) { sidx2[o2] = i; ++o2; }
        if (a3[e]) { sidx3[o3] = i; ++o3; }
    }
    __syncthreads();
    for (int k = tid; k < 384; k += 256) idx2[t * 384 + k] = (k < c2) ? sidx2[k] : -1;
    for (int k = tid; k < 320; k += 256) idx3[t * 320 + k] = (k < c3) ? sidx3[k] : -1;
    for (int k = tid; k < 352; k += 256) {
        int j = (k < c2) ? sidx2[k] : 0;
        cq3[t * 352 + k] = (j % 3) * 352256 + j / 3;
    }
}

// ---- closed-form per-row activation lists ----
template<int C, int NACT>
__global__ __launch_bounds__(256) void kListCF(int* __restrict__ list)
{
    int flat = blockIdx.x * 256 + threadIdx.x;      // row*NACT + s
    if (flat >= 1024 * NACT) return;
    int i = flat / NACT, s = flat % NACT;
    int ri = i % 98;
    int k0 = (98 - ri + C - 1) / C;                 // first wrapped k
    int kw = NACT - k0; if (kw < 0) kw = 0;
    int t = (s < kw) ? (ri + (k0 + s) * C - 98) : (ri + (s - kw) * C);
    int rk = 0;
    int r = t;
#pragma unroll
    for (int k = 0; k < NACT; ++k) {
        rk += (r < i) ? (i - r + 97) / 98 : 0;      // count of i'<i with i'≡r (mod 98)
        r -= C; if (r < 0) r += 98;
    }
    list[i * NACT + s] = (t << 10) | rk;
}

// ---- bit-matrix transpose (layer-1, full range): [t][k][nw] -> [t][kw][n] ----
template<int K>
__global__ __launch_bounds__(256) void kXb(const unsigned* __restrict__ in,
                                           unsigned* __restrict__ out, int t0)
{
    constexpr int Kw = K / 32;
    __shared__ unsigned L[1024];
    int bx = blockIdx.x, tid = threadIdx.x;
    int tt = t0 + bx / Kw, kw = bx % Kw;
    const unsigned* ip = in + ((size_t)tt * K + kw * 32) * 32;
#pragma unroll
    for (int g = 0; g < 4; ++g) L[g * 256 + tid] = ip[g * 256 + tid];
    __syncthreads();
    unsigned* op = out + ((size_t)tt * Kw + kw) * 1024;
#pragma unroll
    for (int g = 0; g < 4; ++g) {
        int n = g * 256 + tid;
        int w = n >> 5, b = n & 31;
        unsigned acc = 0;
#pragma unroll
        for (int k = 0; k < 32; ++k) acc |= ((L[k * 32 + w] >> b) & 1u) << k;
        op[n] = acc;
    }
}

// ---- fused per-chunk: layer-2 bit transpose (11 blocks/t) + layer-3 A-gather (55 blocks/t) ----
__global__ __launch_bounds__(256) void kXbG3A(
    const unsigned* __restrict__ s2b, unsigned* __restrict__ s2bT,
    const ushort* __restrict__ Ws, const int* __restrict__ idx3,
    const int* __restrict__ cq3, ushort* __restrict__ AW3, int t0)
{
    __shared__ unsigned L[1024];
    int bx = blockIdx.x, tid = threadIdx.x;
    int tloc = bx / 66, r66 = bx % 66;
    int t = t0 + tloc;
    if (r66 < 11) {
        int kw = r66;
        const unsigned* ip = s2b + ((size_t)t * 352 + kw * 32) * 32;
#pragma unroll
        for (int g = 0; g < 4; ++g) L[g * 256 + tid] = ip[g * 256 + tid];
        __syncthreads();
        unsigned* op = s2bT + ((size_t)t * 11 + kw) * 1024;
#pragma unroll
        for (int g = 0; g < 4; ++g) {
            int n = g * 256 + tid;
            int w = n >> 5, b = n & 31;
            unsigned acc = 0;
#pragma unroll
            for (int k = 0; k < 32; ++k) acc |= ((L[k * 32 + w] >> b) & 1u) << k;
            op[n] = acc;
        }
    } else {
        int blk = r66 - 11;
        int flat = blk * 256 + tid;      // 0..14079 = 320 rows * 44 k-groups
        int r = flat / 44, kg = flat % 44;
        int k0 = kg * 8;
        int v = idx3[t * 320 + r];
        int i = v < 0 ? 0 : v;           // pad rows: garbage, never read back
        const int* cq = cq3 + t * 352 + k0;
        int c0 = cq[0], c1 = cq[1], c2 = cq[2], c3 = cq[3],
            c4 = cq[4], c5 = cq[5], c6 = cq[6], c7 = cq[7];
        size_t ia = (size_t)i * 344;
#pragma unroll
        for (int pi = 0; pi < 3; ++pi) {
            const ushort* wp = Ws + (size_t)pi * 1056768 + ia;
            union { ushort us[8]; ul2 v2; } o;
            o.us[0] = wp[c0]; o.us[1] = wp[c1]; o.us[2] = wp[c2]; o.us[3] = wp[c3];
            o.us[4] = wp[c4]; o.us[5] = wp[c5]; o.us[6] = wp[c6]; o.us[7] = wp[c7];
            *(ul2*)(AW3 + ((size_t)tloc * 3 + pi) * 112640 + (size_t)r * 352 + k0) = o.v2;
        }
    }
}

// ==================== GEMM bodies (64x64 wave tiles, dbuf, proven round-7 config) ====================

__device__ __forceinline__ void gm2_body(
    int bx, int tid, ushort* AsR,
    const ushort* __restrict__ Ws, const unsigned* __restrict__ s1bT,
    const int* __restrict__ idx2, float* __restrict__ drive, int t0)
{
    int tloc = bx / 24, rem = bx % 24;
    int mt = rem >> 2, nt4 = rem & 3;
    int t = t0 + tloc;
    int p = t & 1;
    int r0 = mt * 64, n0 = nt4 * 256;
    int ar = tid >> 2, ak8 = (tid & 3) * 8;
    int vR = idx2[t * 384 + r0 + ar];
    const ushort* Wrow = Ws + (size_t)p * 524288 + (size_t)(vR < 0 ? 0 : vR) * 512 + ak8;
    int wv = tid >> 6, lane = tid & 63;
    int mrow = lane & 31, kh8 = (lane >> 5) * 8;
    int nb = n0 + wv * 64 + mrow;
    f16v acc[2][2];
#pragma unroll
    for (int a = 0; a < 2; ++a)
#pragma unroll
        for (int b = 0; b < 2; ++b) acc[a][b] = (f16v)(0.f);

    ul2 c0r[3];
#pragma unroll
    for (int pi = 0; pi < 3; ++pi) c0r[pi] = *(const ul2*)(Wrow + (size_t)pi * 1048576);
#pragma unroll
    for (int pi = 0; pi < 3; ++pi) ldsWR(&AsR[ASOFF(0, pi, ar, ak8)], c0r[pi]);
    ul2 nxt[3];
#pragma unroll
    for (int pi = 0; pi < 3; ++pi) nxt[pi] = *(const ul2*)(Wrow + (size_t)pi * 1048576 + 32);
    unsigned w4c[2];
#pragma unroll
    for (int jj = 0; jj < 2; ++jj) w4c[jj] = s1bT[(size_t)t * 16 * 1024 + nb + jj * 32];
    __syncthreads();

    int cur = 0;
    for (int kc = 0; kc < 512; kc += 32) {
        if (kc + 32 < 512) {
#pragma unroll
            for (int pi = 0; pi < 3; ++pi) ldsWR(&AsR[ASOFF(cur ^ 1, pi, ar, ak8)], nxt[pi]);
        }
        unsigned w4n[2];
        if (kc + 32 < 512) {
#pragma unroll
            for (int jj = 0; jj < 2; ++jj)
                w4n[jj] = s1bT[((size_t)t * 16 + ((kc + 32) >> 5)) * 1024 + nb + jj * 32];
        }
        ul2 n2[3];
        if (kc + 64 < 512) {
#pragma unroll
            for (int pi = 0; pi < 3; ++pi)
                n2[pi] = *(const ul2*)(Wrow + (size_t)pi * 1048576 + kc + 64);
        }
#pragma unroll
        for (int s2 = 0; s2 < 2; ++s2) {
            int kcol = s2 * 16 + kh8;
            short8 bf[2];
#pragma unroll
            for (int jj = 0; jj < 2; ++jj) bf[jj] = expand8((w4c[jj] >> kcol) & 0xFFu);
#pragma unroll
            for (int wr2 = 0; wr2 < 2; ++wr2) {
                short8 af0 = ldsAF(&AsR[ASOFF(cur, 0, wr2 * 32 + mrow, kcol)]);
                short8 af1 = ldsAF(&AsR[ASOFF(cur, 1, wr2 * 32 + mrow, kcol)]);
                short8 af2 = ldsAF(&AsR[ASOFF(cur, 2, wr2 * 32 + mrow, kcol)]);
#pragma unroll
                for (int jj = 0; jj < 2; ++jj) {
                    acc[wr2][jj] = __builtin_amdgcn_mfma_f32_32x32x16_bf16(af2, bf[jj], acc[wr2][jj], 0, 0, 0);
                    acc[wr2][jj] = __builtin_amdgcn_mfma_f32_32x32x16_bf16(af1, bf[jj], acc[wr2][jj], 0, 0, 0);
                    acc[wr2][jj] = __builtin_amdgcn_mfma_f32_32x32x16_bf16(af0, bf[jj], acc[wr2][jj], 0, 0, 0);
                }
            }
        }
        __syncthreads();
        cur ^= 1;
        nxt[0] = n2[0]; nxt[1] = n2[1]; nxt[2] = n2[2];
        w4c[0] = w4n[0]; w4c[1] = w4n[1];
    }
#pragma unroll
    for (int wr2 = 0; wr2 < 2; ++wr2)
#pragma unroll
        for (int jj = 0; jj < 2; ++jj)
#pragma unroll
            for (int reg = 0; reg < 16; ++reg) {
                int rowl = r0 + wr2 * 32 + (reg & 3) + 8 * (reg >> 2) + 4 * (lane >> 5);
                drive[((size_t)tloc * 384 + rowl) * 1024 + nb + jj * 32] = acc[wr2][jj][reg];
            }
}

__device__ __forceinline__ void gm3_body(
    int bx, int tid, ushort* AsR,
    const ushort* __restrict__ AW3, const unsigned* __restrict__ s2bT,
    float* __restrict__ drive, int t0)
{
    int tloc = bx / 20, rem = bx % 20;
    int mt = rem >> 2, nt4 = rem & 3;
    int t = t0 + tloc;
    int r0 = mt * 64, n0 = nt4 * 256;
    int ar = tid >> 2, ak8 = (tid & 3) * 8;
    const ushort* Ab = AW3 + (size_t)tloc * 337920 + (size_t)(r0 + ar) * 352 + ak8;
    int wv = tid >> 6, lane = tid & 63;
    int mrow = lane & 31, kh8 = (lane >> 5) * 8;
    int nb = n0 + wv * 64 + mrow;
    f16v acc[2][2];
#pragma unroll
    for (int a = 0; a < 2; ++a)
#pragma unroll
        for (int b = 0; b < 2; ++b) acc[a][b] = (f16v)(0.f);

    ul2 c0r[3];
#pragma unroll
    for (int pi = 0; pi < 3; ++pi) c0r[pi] = *(const ul2*)(Ab + (size_t)pi * 112640);
#pragma unroll
    for (int pi = 0; pi < 3; ++pi) ldsWR(&AsR[ASOFF(0, pi, ar, ak8)], c0r[pi]);
    ul2 nxt[3];
#pragma unroll
    for (int pi = 0; pi < 3; ++pi) nxt[pi] = *(const ul2*)(Ab + (size_t)pi * 112640 + 32);
    unsigned w4c[2];
#pragma unroll
    for (int jj = 0; jj < 2; ++jj) w4c[jj] = s2bT[(size_t)t * 11 * 1024 + nb + jj * 32];
    __syncthreads();

    int cur = 0;
    for (int kc = 0; kc < 352; kc += 32) {
        if (kc + 32 < 352) {
#pragma unroll
            for (int pi = 0; pi < 3; ++pi) ldsWR(&AsR[ASOFF(cur ^ 1, pi, ar, ak8)], nxt[pi]);
        }
        unsigned w4n[2];
        if (kc + 32 < 352) {
#pragma unroll
            for (int jj = 0; jj < 2; ++jj)
                w4n[jj] = s2bT[((size_t)t * 11 + ((kc + 32) >> 5)) * 1024 + nb + jj * 32];
        }
        ul2 n2[3];
        if (kc + 64 < 352) {
#pragma unroll
            for (int pi = 0; pi < 3; ++pi)
                n2[pi] = *(const ul2*)(Ab + (size_t)pi * 112640 + kc + 64);
        }
#pragma unroll
        for (int s2 = 0; s2 < 2; ++s2) {
            int kcol = s2 * 16 + kh8;
            short8 bf[2];
#pragma unroll
            for (int jj = 0; jj < 2; ++jj) bf[jj] = expand8((w4c[jj] >> kcol) & 0xFFu);
#pragma unroll
            for (int wr2 = 0; wr2 < 2; ++wr2) {
                short8 af0 = ldsAF(&AsR[ASOFF(cur, 0, wr2 * 32 + mrow, kcol)]);
                short8 af1 = ldsAF(&AsR[ASOFF(cur, 1, wr2 * 32 + mrow, kcol)]);
                short8 af2 = ldsAF(&AsR[ASOFF(cur, 2, wr2 * 32 + mrow, kcol)]);
#pragma unroll
                for (int jj = 0; jj < 2; ++jj) {
                    acc[wr2][jj] = __builtin_amdgcn_mfma_f32_32x32x16_bf16(af2, bf[jj], acc[wr2][jj], 0, 0, 0);
                    acc[wr2][jj] = __builtin_amdgcn_mfma_f32_32x32x16_bf16(af1, bf[jj], acc[wr2][jj], 0, 0, 0);
                    acc[wr2][jj] = __builtin_amdgcn_mfma_f32_32x32x16_bf16(af0, bf[jj], acc[wr2][jj], 0, 0, 0);
                }
            }
        }
        __syncthreads();
        cur ^= 1;
        nxt[0] = n2[0]; nxt[1] = n2[1]; nxt[2] = n2[2];
        w4c[0] = w4n[0]; w4c[1] = w4n[1];
    }
#pragma unroll
    for (int wr2 = 0; wr2 < 2; ++wr2)
#pragma unroll
        for (int jj = 0; jj < 2; ++jj)
#pragma unroll
            for (int reg = 0; reg < 16; ++reg) {
                int rowl = r0 + wr2 * 32 + (reg & 3) + 8 * (reg >> 2) + 4 * (lane >> 5);
                drive[((size_t)tloc * 320 + rowl) * 1024 + nb + jj * 32] = acc[wr2][jj][reg];
            }
}

// standalone wrappers (prologue GM2 / epilogue GM3)
__global__ __launch_bounds__(256) void kGM2K(
    const ushort* __restrict__ Ws, const unsigned* __restrict__ s1bT,
    const int* __restrict__ idx2, float* __restrict__ drive, int t0)
{
    __shared__ ushort AsR[2 * 3 * 64 * 36];
    gm2_body(blockIdx.x, threadIdx.x, AsR, Ws, s1bT, idx2, drive, t0);
}
__global__ __launch_bounds__(256) void kGM3K(
    const ushort* __restrict__ AW3, const unsigned* __restrict__ s2bT,
    float* __restrict__ drive, int t0)
{
    __shared__ ushort AsR[2 * 3 * 64 * 36];
    gm3_body(blockIdx.x, threadIdx.x, AsR, AW3, s2bT, drive, t0);
}

// fused cross-chunk GEMM: GM2(chunk c+1) blocks first (longer, LPT), then GM3(chunk c)
__global__ __launch_bounds__(256) void kGMF(
    const ushort* __restrict__ W2S, const unsigned* __restrict__ s1bT,
    const int* __restrict__ idx2, float* __restrict__ drv2, int t0_2, int n2blocks,
    const ushort* __restrict__ AW3, const unsigned* __restrict__ s2bT,
    float* __restrict__ drv3, int t0_3)
{
    __shared__ ushort AsR[2 * 3 * 64 * 36];
    int bx = blockIdx.x;
    if (bx < n2blocks) gm2_body(bx, threadIdx.x, AsR, W2S, s1bT, idx2, drv2, t0_2);
    else               gm3_body(bx - n2blocks, threadIdx.x, AsR, AW3, s2bT, drv3, t0_3);
}

// ---- chunk recurrence body: one wave per (row, 64-col block), depth-2 drive prefetch ----
template<int MP, int KBP, bool BITS, int NACT>
__device__ __forceinline__ void rk_body(
    int bx, int tid,
    const float* __restrict__ drive, const float* __restrict__ bias,
    const int* __restrict__ list,
    float* __restrict__ mG, float* __restrict__ ssG,
    unsigned long long* __restrict__ bitsOut, int t0, int nt)
{
    int row = bx >> 2;                               // 0..1023
    int wv  = ((bx & 3) << 2) + (tid >> 6);          // nblk 0..15
    int lane = tid & 63;
    int n = (wv << 6) + lane;
    size_t idx = (size_t)row * 1024 + n;
    float mv = mG[idx];
    float cnt = 0.f;
    float bv = bias[row];
    const int* lp = list + row * NACT;               // wave-uniform -> scalar loads
    int t1 = t0 + nt;
    int s0 = 0;
    while (s0 < NACT && (lp[s0] >> 10) < t0) ++s0;
    int s1 = s0;
    while (s1 < NACT && (lp[s1] >> 10) < t1) ++s1;
    if (s0 < s1) {
        int v0 = lp[s0];
        float d0 = drive[((size_t)((v0 >> 10) - t0) * MP + (v0 & 1023)) * 1024 + n];
        int v1 = 0; float d1 = 0.f;
        if (s0 + 1 < s1) {
            v1 = lp[s0 + 1];
            d1 = drive[((size_t)((v1 >> 10) - t0) * MP + (v1 & 1023)) * 1024 + n];
        }
        for (int s = s0; s < s1; ++s) {
            int vc = v0;
            float dcur = d0;
            v0 = v1; d0 = d1;
            if (s + 2 < s1) {
                v1 = lp[s + 2];
                d1 = drive[((size_t)((v1 >> 10) - t0) * MP + (v1 & 1023)) * 1024 + n];
            }
            float d = dcur + bv;
            float m = mv * 0.5f + d;
            mv = m;
            bool sp = m > 0.5f;
            if (BITS) {
                unsigned long long bm = __ballot(sp);
                if (lane == 0) bitsOut[((size_t)(vc >> 10) * KBP + (vc & 1023)) * 16 + wv] = bm;
            }
            cnt += sp ? 1.f : 0.f;
        }
    }
    mG[idx] = mv;
    ssG[idx] += cnt;
}

template<int MP, int KBP, bool BITS, int NACT>
__global__ __launch_bounds__(256) void kRK(
    const float* __restrict__ drive, const float* __restrict__ bias,
    const int* __restrict__ list,
    float* __restrict__ mG, float* __restrict__ ssG,
    unsigned long long* __restrict__ bitsOut, int t0, int nt)
{
    rk_body<MP, KBP, BITS, NACT>(blockIdx.x, threadIdx.x, drive, bias, list,
                                 mG, ssG, bitsOut, t0, nt);
}

// fused cross-chunk recurrence: RK3(chunk c) [4096 blocks] + RK2(chunk c+1) [4096 blocks]
__global__ __launch_bounds__(256) void kRKF(
    const float* __restrict__ drv3, const float* __restrict__ b3,
    const int* __restrict__ list3, float* __restrict__ m3, float* __restrict__ ss3,
    int t0_3, int nt3,
    const float* __restrict__ drv2, const float* __restrict__ b2,
    const int* __restrict__ list2, float* __restrict__ m2, float* __restrict__ ss2,
    unsigned long long* __restrict__ s2bits, int t0_2, int nt2)
{
    int bx = blockIdx.x;
    if (bx < 4096)
        rk_body<320, 0, false, 25>(bx, threadIdx.x, drv3, b3, list3, m3, ss3,
                                   nullptr, t0_3, nt3);
    else
        rk_body<384, 352, true, 33>(bx - 4096, threadIdx.x, drv2, b2, list2, m2, ss2,
                                    s2bits, t0_2, nt2);
}

// ---- tail: ss transposes + fr; W4 GEMV partials into osum ----
__global__ __launch_bounds__(256) void kTail(
    const float* __restrict__ ssBase, const float* __restrict__ W4,
    float* __restrict__ osum, float* __restrict__ out, float* __restrict__ fr)
{
    int bx = blockIdx.x, tid = threadIdx.x;
    if (bx < 768) {
        __shared__ float Ls[64][65];
        __shared__ float red[4];
        int l = bx >> 8;
        int tile = bx & 255;
        int i0 = (tile >> 4) * 64, n0 = (tile & 15) * 64;
        const float* ss = ssBase + (size_t)l * MM;
        float* o = out + 10240 + (size_t)l * MM;
        float sum = 0.f;
#pragma unroll
        for (int j = 0; j < 16; ++j) {
            int flat = tid + 256 * j;
            int a = flat >> 6, c = flat & 63;
            float v = ss[(size_t)(i0 + a) * 1024 + n0 + c];
            Ls[a][c] = v;
            sum += v;
        }
        __syncthreads();
        for (int off = 32; off > 0; off >>= 1) sum += __shfl_down(sum, off, 64);
        if ((tid & 63) == 0) red[tid >> 6] = sum;
        __syncthreads();
        if (tid == 0) {
            float s = red[0] + red[1] + red[2] + red[3];
            atomicAdd(&fr[l], s * (1.0f / (1024.0f * 1024.0f * 98.0f)));
        }
#pragma unroll
        for (int j = 0; j < 16; ++j) {
            int flat = tid + 256 * j;
            int nn = flat >> 6, ii = flat & 63;
            o[(size_t)(n0 + nn) * 1024 + i0 + ii] = Ls[ii][nn] * (1.0f / 98.0f);
        }
    } else {
        int b = bx - 768;
        int ks = b >> 4, nt = b & 15;
        int n = nt * 64 + (tid & 63);
        int og = tid >> 6;
        const float* ss3 = ssBase + (size_t)2 * MM;
        float a0 = 0.f, a1 = 0.f, a2 = 0.f;
        int k0 = ks * 256;
        for (int k = k0; k < k0 + 256; ++k) {
            float v = ss3[(size_t)k * 1024 + n];
            a0 += v * W4[og * 1024 + k];
            a1 += v * W4[(og + 4) * 1024 + k];
            if (og < 2) a2 += v * W4[(og + 8) * 1024 + k];
        }
        atomicAdd(&osum[n * OUTD + og], a0);
        atomicAdd(&osum[n * OUTD + og + 4], a1);
        if (og < 2) atomicAdd(&osum[n * OUTD + og + 8], a2);
    }
}

__global__ void kOut(const float* __restrict__ osum, const float* __restrict__ b4,
                     float* __restrict__ out)
{
    int idx = blockIdx.x * 256 + threadIdx.x;
    if (idx < 1024 * OUTD) out[idx] = osum[idx] * (1.0f / 98.0f) + b4[idx % OUTD];
}

extern "C" void kernel_launch(void* const* d_in, const int* in_sizes, int n_in,
                              void* d_out, int out_size, void* d_ws, size_t ws_size,
                              hipStream_t stream)
{
    const float* input = (const float*)d_in[0];
    const float* W1    = (const float*)d_in[1];
    const float* b1    = (const float*)d_in[2];
    const float* W2    = (const float*)d_in[3];
    const float* b2    = (const float*)d_in[4];
    const float* W3    = (const float*)d_in[5];
    const float* b3    = (const float*)d_in[6];
    const float* W4    = (const float*)d_in[7];
    const float* b4    = (const float*)d_in[8];

    float* ws = (float*)d_ws;
    float* ss1  = ws;
    float* ss2  = ws + MM;
    float* ss3  = ws + 2 * MM;
    float* m2   = ws + 3 * MM;
    float* m3   = ws + 4 * MM;
    float* osum = ws + OFF_OSUM;
    float* xT   = ws + OFF_XT;
    int*   tabs = (int*)(ws + OFF_XT);   // reuses xT region after kL1
    int* idx2  = tabs + TAB_IDX2;
    int* idx3  = tabs + TAB_IDX3;
    int* cq3   = tabs + TAB_CQ3;
    int* list2 = tabs + TAB_L2;
    int* list3 = tabs + TAB_L3;
    unsigned int* s1b  = (unsigned int*)(ws + OFF_S1B);
    unsigned int* s2b  = (unsigned int*)(ws + OFF_S2B);
    unsigned int* s1bT = (unsigned int*)(ws + OFF_S1BT);
    unsigned int* s2bT = (unsigned int*)(ws + OFF_S2BT);
    ushort* W2S = (ushort*)(ws + OFF_W2S);
    ushort* W3S = (ushort*)(ws + OFF_W3S);
    float* out  = (float*)d_out;

    // pick the largest t-chunk the workspace can hold.
    size_t availF = ws_size / sizeof(float);
    constexpr size_t PER_T = AW3_PER_T + 384 * 1024 + 320 * 1024;   // 889,856 floats
    int tc = 10;   // guaranteed-fit fallback (~94 MB)
    const int cands[8] = {98, 66, 49, 40, 33, 25, 14, 10};
    for (int ci = 0; ci < 8; ++ci) {
        if (FIX_END + (size_t)cands[ci] * PER_T <= availF) { tc = cands[ci]; break; }
    }
    ushort* AW3 = (ushort*)(ws + FIX_END);
    float* drv2 = ws + FIX_END + (size_t)tc * AW3_PER_T;
    float* drv3 = drv2 + (size_t)tc * 384 * 1024;

    hipMemsetAsync(ws, 0, (5 * MM + 10240) * sizeof(float), stream);   // ss, m2, m3, osum
    hipMemsetAsync(s2b, 0, 1103872 * sizeof(unsigned int), stream);    // layer-2 bits (pad ranks)
    hipMemsetAsync(out + 3155968, 0, 3 * sizeof(float), stream);       // fr

    kSplit<<<8224, 256, 0, stream>>>(W2, W3, W2S, W3S);
    kPrep<<<208, 256, 0, stream>>>(input, xT);
    kL1<<<1024, 256, 0, stream>>>(xT, W1, b1, (unsigned long long*)s1b, ss1);
    kTab2<<<98, 256, 0, stream>>>(idx2, idx3, cq3);                    // after kL1: reuses xT mem
    kListCF<3, 33><<<132, 256, 0, stream>>>(list2);
    kListCF<4, 25><<<100, 256, 0, stream>>>(list3);
    kXb<512><<<1568, 256, 0, stream>>>(s1b, s1bT, 0);

    int nc = (TTL + tc - 1) / tc;
    auto ntOf = [&](int c) { int t0c = c * tc; return (TTL - t0c < tc) ? (TTL - t0c) : tc; };

    // software pipeline with cross-chunk fusion:
    //   GM2(0), RK2(0), X(0), { GMF[GM2(c+1)+GM3(c)], RKF[RK3(c)+RK2(c+1)], X(c+1) }, GM3(last), RK3(last)
    kGM2K<<<ntOf(0) * 24, 256, 0, stream>>>(W2S, s1bT, idx2, drv2, 0);
    kRK<384, 352, true, 33><<<4096, 256, 0, stream>>>(drv2, b2, list2, m2, ss2,
                                                      (unsigned long long*)s2b, 0, ntOf(0));
    kXbG3A<<<ntOf(0) * 66, 256, 0, stream>>>(s2b, s2bT, W3S, idx3, cq3, AW3, 0);

    for (int c = 0; c + 1 < nc; ++c) {
        int t03 = c * tc, t02 = (c + 1) * tc;
        int n2b = ntOf(c + 1) * 24, n3b = ntOf(c) * 20;
        kGMF<<<n2b + n3b, 256, 0, stream>>>(W2S, s1bT, idx2, drv2, t02, n2b,
                                            AW3, s2bT, drv3, t03);
        kRKF<<<8192, 256, 0, stream>>>(drv3, b3, list3, m3, ss3, t03, ntOf(c),
                                       drv2, b2, list2, m2, ss2,
                                       (unsigned long long*)s2b, t02, ntOf(c + 1));
        kXbG3A<<<ntOf(c + 1) * 66, 256, 0, stream>>>(s2b, s2bT, W3S, idx3, cq3, AW3, t02);
    }
    int cl = nc - 1, t0l = cl * tc;
    kGM3K<<<ntOf(cl) * 20, 256, 0, stream>>>(AW3, s2bT, drv3, t0l);
    kRK<320, 0, false, 25><<<4096, 256, 0, stream>>>(drv3, b3, list3, m3, ss3,
                                                     nullptr, t0l, ntOf(cl));

    kTail<<<832, 256, 0, stream>>>(ss1, W4, osum, out, out + 3155968);
    kOut<<<40, 256, 0, stream>>>(osum, b4, out);
}

// Round 15
// 507.935 us; speedup vs baseline: 1.3312x; 1.0188x over previous
//
#include <hip/hip_runtime.h>

#define TTL 98
#define OUTD 10

typedef float f16v __attribute__((ext_vector_type(16)));
typedef short short8 __attribute__((ext_vector_type(8)));
typedef unsigned long ul2 __attribute__((ext_vector_type(2)));
typedef unsigned short ushort;

constexpr size_t MM = 1048576;
constexpr size_t OFF_OSUM = 5 * MM;                  // 10,240
constexpr size_t OFF_XT   = OFF_OSUM + 10240;        // 802,816 (tables reuse after kL1)
constexpr size_t OFF_S1B  = OFF_XT + 802816;         // u32: 98*512*32
constexpr size_t OFF_S2B  = OFF_S1B + 1605632;       // u32: 98*352*32
constexpr size_t OFF_S1BT = OFF_S2B + 1103872;       // u32: 98*16*1024 (bit-transposed L1)
constexpr size_t OFF_S2BT = OFF_S1BT + 1605632;      // u32: 98*11*1024 (bit-transposed L2)
constexpr size_t OFF_W2S  = OFF_S2BT + 1103872;      // bf16 3*2*1024*512
constexpr size_t OFF_W3S  = OFF_W2S + 1572864;       // bf16 3*3*1024*344
constexpr size_t FIX_END  = OFF_W3S + 1585152;       // 14,632,960 floats (58.5 MB)

constexpr size_t TAB_IDX2 = 0;        // 98*384
constexpr size_t TAB_IDX3 = 37632;    // 98*320
constexpr size_t TAB_CQ3  = 269696;   // 98*352
constexpr size_t TAB_L2   = 304192;   // 1024*33 packed (t<<10|rk), exactly 33 per row
constexpr size_t TAB_L3   = 337984;   // 1024*25 packed, exactly 25 per row

// AW3 per-t footprint: 3 * 320 * 352 ushort = 337,920 ushort = 168,960 floats (FULL size).
constexpr size_t AW3_PER_T = 168960;

// ---- exact 3-way bf16 split by truncation: hi+mid+lo == w bit-exactly ----
__device__ inline void split3(float w, ushort& h, ushort& m, ushort& l) {
    unsigned u = __float_as_uint(w);
    h = (ushort)(u >> 16);
    float r1 = w - __uint_as_float(u & 0xFFFF0000u);
    unsigned u1 = __float_as_uint(r1);
    m = (ushort)(u1 >> 16);
    float r2 = r1 - __uint_as_float(u1 & 0xFFFF0000u);
    l = (ushort)(__float_as_uint(r2) >> 16);
}

// ---- 8 spike bits -> short8 of bf16 {0,1} (element e = bit e) ----
__device__ inline short8 expand8(unsigned x) {
    union { unsigned u[4]; short8 v; } r;
#pragma unroll
    for (int q = 0; q < 4; ++q) {
        unsigned b = x >> (2 * q);
        r.u[q] = ((b & 1u) * 0x3F80u) | ((b & 2u) ? 0x3F800000u : 0u);
    }
    return r.v;
}

// ---- LDS helpers: 72B-stride rows -> b64 pairs ----
__device__ inline short8 ldsAF(const ushort* base) {
    union { unsigned long u[2]; short8 s; } r;
    r.u[0] = *(const unsigned long*)(base);
    r.u[1] = *(const unsigned long*)(base + 4);
    return r.s;
}
__device__ inline void ldsWR(ushort* dst, ul2 v) {
    *(unsigned long*)(dst) = v[0];
    *(unsigned long*)(dst + 4) = v[1];
}
// As layout (raw): [cur][pi][row][col36]
#define ASOFF(cur, pi, row, col) (((((cur)*3 + (pi))*64 + (row))*36) + (col))

// ---- bijective XCD-aware block swizzle (m204 variant): consecutive WORK ids land on
// the same XCD so the 4 nt4-sibling blocks sharing an A-tile hit one L2, not four. ----
__device__ __forceinline__ int xcdSwz(int bx, int nwg) {
    int q = nwg >> 3, r = nwg & 7;
    int x = bx & 7, o = bx >> 3;
    return (x < r ? x * (q + 1) : r * (q + 1) + (x - r) * q) + o;
}

// ---- split weights: W2S[pi][p][i][q] (j=2q+p), W3S[pi][c][i][q] (j=c+3q) ----
__global__ __launch_bounds__(256) void kSplit(
    const float* __restrict__ W2, const float* __restrict__ W3,
    ushort* __restrict__ W2S, ushort* __restrict__ W3S)
{
    int id = blockIdx.x * 256 + threadIdx.x;
    if (id < 1048576) {
        int p = id >> 19, rem = id & 524287, i = rem >> 9, q = rem & 511;
        ushort h, m, l;
        split3(W2[i * 1024 + 2 * q + p], h, m, l);
        size_t base = (size_t)p * 524288 + (size_t)i * 512 + q;
        W2S[base] = h; W2S[base + 1048576] = m; W2S[base + 2097152] = l;
    } else {
        int id2 = id - 1048576;
        if (id2 >= 1056768) return;
        int c = id2 / 352256, rem = id2 % 352256, i = rem / 344, q = rem % 344;
        int j = c + 3 * q;
        float w = (j < 1024) ? W3[i * 1024 + j] : 0.f;
        ushort h, m, l;
        split3(w, h, m, l);
        W3S[id2] = h; W3S[id2 + 1056768] = m; W3S[id2 + 2113536] = l;
    }
}

// ---- transpose input -> xT[784][1024] ----
__global__ __launch_bounds__(256) void kPrep(const float* __restrict__ input,
                                             float* __restrict__ xT)
{
    __shared__ float Ls[64][65];
    int bx = blockIdx.x, tid = threadIdx.x;
    int wt = bx >> 4, nt = bx & 15;
    int w0 = wt * 64, n0 = nt * 64;
#pragma unroll
    for (int j = 0; j < 16; ++j) {
        int flat = tid + 256 * j;
        int a = flat >> 6, c = flat & 63;
        Ls[a][c] = (w0 + c < 784) ? input[(size_t)(n0 + a) * 784 + w0 + c] : 0.f;
    }
    __syncthreads();
#pragma unroll
    for (int j = 0; j < 16; ++j) {
        int flat = tid + 256 * j;
        int ii = flat >> 6, nn = flat & 63;
        if (w0 + ii < 784) xT[(size_t)(w0 + ii) * 1024 + n0 + nn] = Ls[nn][ii];
    }
}

// ---- layer-1: phase A (t<12, varying window) + phase B (t>=12, constant window) ----
__global__ __launch_bounds__(256) void kL1(
    const float* __restrict__ xT, const float* __restrict__ W1,
    const float* __restrict__ b1,
    unsigned long long* __restrict__ s1bits, float* __restrict__ ss1)
{
    int tid = threadIdx.x;
    int waveId = (blockIdx.x << 2) + (tid >> 6);   // 0..4095
    int lane = tid & 63;
    int rowg = waveId >> 4;                        // 0..255
    int nblk = waveId & 15;
    int i0 = rowg << 2;
    int n = (nblk << 6) + lane;
    float w[4][8], bb[4], mem[4], cnt[4];
#pragma unroll
    for (int r = 0; r < 4; ++r) {
#pragma unroll
        for (int e = 0; e < 8; ++e) w[r][e] = W1[(i0 + r) * 8 + e];
        bb[r] = b1[i0 + r]; mem[r] = 0.f; cnt[r] = 0.f;
    }
    float x[8], xn[8];
#pragma unroll
    for (int e = 0; e < 8; ++e) x[e] = xT[(size_t)e * 1024 + n];
    for (int t = 0; t < 12; ++t) {
        int st1 = ((t + 1) * 8 < TTL - 8) ? (t + 1) * 8 : (784 - 8);
#pragma unroll
        for (int e = 0; e < 8; ++e) xn[e] = xT[(size_t)(st1 + e) * 1024 + n];
#pragma unroll
        for (int r = 0; r < 4; ++r) {
            if (((t ^ (i0 + r)) & 1) == 0) {       // parity rule exact for cycle 2 (98 even)
                float d = bb[r];
#pragma unroll
                for (int e = 0; e < 8; ++e) d += w[r][e] * x[e];
                float m = mem[r] * 0.5f + d;       // prev spike provably 0 at active steps
                mem[r] = m;
                bool sp = m > 0.5f;
                unsigned long long bm = __ballot(sp);
                if (lane == 0) s1bits[(size_t)(t * 512 + ((i0 + r) >> 1)) * 16 + nblk] = bm;
                if (sp) cnt[r] += 1.f;
            }
        }
#pragma unroll
        for (int e = 0; e < 8; ++e) x[e] = xn[e];
    }
    float dd[4];
#pragma unroll
    for (int r = 0; r < 4; ++r) {
        float d = bb[r];
#pragma unroll
        for (int e = 0; e < 8; ++e) d += w[r][e] * x[e];
        dd[r] = d;
    }
#pragma unroll 1
    for (int t = 12; t < TTL; t += 2) {            // t even: rows 0,2 ; t+1: rows 1,3
#pragma unroll
        for (int h = 0; h < 2; ++h) {
#pragma unroll
            for (int rr = 0; rr < 2; ++rr) {
                int r = h + rr * 2;
                float m = mem[r] * 0.5f + dd[r];
                mem[r] = m;
                bool sp = m > 0.5f;
                unsigned long long bm = __ballot(sp);
                if (lane == 0) s1bits[(size_t)((t + h) * 512 + ((i0 + r) >> 1)) * 16 + nblk] = bm;
                if (sp) cnt[r] += 1.f;
            }
        }
    }
#pragma unroll
    for (int r = 0; r < 4; ++r) ss1[(size_t)(i0 + r) * 1024 + n] = cnt[r];
}

// ---- per-t tables via prefix scan: u=(t-i) mod 98 (98%3,4 != 0 -> table, not residue) ----
__global__ __launch_bounds__(256) void kTab2(
    int* __restrict__ idx2, int* __restrict__ idx3, int* __restrict__ cq3)
{
    __shared__ int f2[256], f3[256];
    __shared__ int sidx2[384], sidx3[320];
    int t = blockIdx.x, tid = threadIdx.x;
    int a2[4], a3[4];
    int l2 = 0, l3 = 0;
#pragma unroll
    for (int e = 0; e < 4; ++e) {
        int i = tid * 4 + e;
        int u = (t - i) % TTL; if (u < 0) u += TTL;
        a2[e] = (u % 3 == 0); a3[e] = (u % 4 == 0);
        l2 += a2[e]; l3 += a3[e];
    }
    f2[tid] = l2; f3[tid] = l3;
    __syncthreads();
    for (int s = 1; s < 256; s <<= 1) {
        int v2 = (tid >= s) ? f2[tid - s] : 0;
        int v3 = (tid >= s) ? f3[tid - s] : 0;
        __syncthreads();
        f2[tid] += v2; f3[tid] += v3;
        __syncthreads();
    }
    int o2 = f2[tid] - l2, o3 = f3[tid] - l3;
    int c2 = f2[255], c3 = f3[255];
#pragma unroll
    for (int e = 0; e < 4; ++e) {
        int i = tid * 4 + e;
        if (a2[e]) { sidx2[o2] = i; ++o2; }
        if (a3[e]) { sidx3[o3] = i; ++o3; }
    }
    __syncthreads();
    for (int k = tid; k < 384; k += 256) idx2[t * 384 + k] = (k < c2) ? sidx2[k] : -1;
    for (int k = tid; k < 320; k += 256) idx3[t * 320 + k] = (k < c3) ? sidx3[k] : -1;
    for (int k = tid; k < 352; k += 256) {
        int j = (k < c2) ? sidx2[k] : 0;
        cq3[t * 352 + k] = (j % 3) * 352256 + j / 3;
    }
}

// ---- closed-form per-row activation lists ----
template<int C, int NACT>
__global__ __launch_bounds__(256) void kListCF(int* __restrict__ list)
{
    int flat = blockIdx.x * 256 + threadIdx.x;      // row*NACT + s
    if (flat >= 1024 * NACT) return;
    int i = flat / NACT, s = flat % NACT;
    int ri = i % 98;
    int k0 = (98 - ri + C - 1) / C;                 // first wrapped k
    int kw = NACT - k0; if (kw < 0) kw = 0;
    int t = (s < kw) ? (ri + (k0 + s) * C - 98) : (ri + (s - kw) * C);
    int rk = 0;
    int r = t;
#pragma unroll
    for (int k = 0; k < NACT; ++k) {
        rk += (r < i) ? (i - r + 97) / 98 : 0;      // count of i'<i with i'≡r (mod 98)
        r -= C; if (r < 0) r += 98;
    }
    list[i * NACT + s] = (t << 10) | rk;
}

// ---- bit-matrix transpose (layer-1, full range): [t][k][nw] -> [t][kw][n] ----
template<int K>
__global__ __launch_bounds__(256) void kXb(const unsigned* __restrict__ in,
                                           unsigned* __restrict__ out, int t0)
{
    constexpr int Kw = K / 32;
    __shared__ unsigned L[1024];
    int bx = blockIdx.x, tid = threadIdx.x;
    int tt = t0 + bx / Kw, kw = bx % Kw;
    const unsigned* ip = in + ((size_t)tt * K + kw * 32) * 32;
#pragma unroll
    for (int g = 0; g < 4; ++g) L[g * 256 + tid] = ip[g * 256 + tid];
    __syncthreads();
    unsigned* op = out + ((size_t)tt * Kw + kw) * 1024;
#pragma unroll
    for (int g = 0; g < 4; ++g) {
        int n = g * 256 + tid;
        int w = n >> 5, b = n & 31;
        unsigned acc = 0;
#pragma unroll
        for (int k = 0; k < 32; ++k) acc |= ((L[k * 32 + w] >> b) & 1u) << k;
        op[n] = acc;
    }
}

// ---- fused per-chunk: layer-2 bit transpose (11 blocks/t) + layer-3 A-gather (55 blocks/t) ----
__global__ __launch_bounds__(256) void kXbG3A(
    const unsigned* __restrict__ s2b, unsigned* __restrict__ s2bT,
    const ushort* __restrict__ Ws, const int* __restrict__ idx3,
    const int* __restrict__ cq3, ushort* __restrict__ AW3, int t0)
{
    __shared__ unsigned L[1024];
    int bx = blockIdx.x, tid = threadIdx.x;
    int tloc = bx / 66, r66 = bx % 66;
    int t = t0 + tloc;
    if (r66 < 11) {
        int kw = r66;
        const unsigned* ip = s2b + ((size_t)t * 352 + kw * 32) * 32;
#pragma unroll
        for (int g = 0; g < 4; ++g) L[g * 256 + tid] = ip[g * 256 + tid];
        __syncthreads();
        unsigned* op = s2bT + ((size_t)t * 11 + kw) * 1024;
#pragma unroll
        for (int g = 0; g < 4; ++g) {
            int n = g * 256 + tid;
            int w = n >> 5, b = n & 31;
            unsigned acc = 0;
#pragma unroll
            for (int k = 0; k < 32; ++k) acc |= ((L[k * 32 + w] >> b) & 1u) << k;
            op[n] = acc;
        }
    } else {
        int blk = r66 - 11;
        int flat = blk * 256 + tid;      // 0..14079 = 320 rows * 44 k-groups
        int r = flat / 44, kg = flat % 44;
        int k0 = kg * 8;
        int v = idx3[t * 320 + r];
        int i = v < 0 ? 0 : v;           // pad rows: garbage, never read back
        const int* cq = cq3 + t * 352 + k0;
        int c0 = cq[0], c1 = cq[1], c2 = cq[2], c3 = cq[3],
            c4 = cq[4], c5 = cq[5], c6 = cq[6], c7 = cq[7];
        size_t ia = (size_t)i * 344;
#pragma unroll
        for (int pi = 0; pi < 3; ++pi) {
            const ushort* wp = Ws + (size_t)pi * 1056768 + ia;
            union { ushort us[8]; ul2 v2; } o;
            o.us[0] = wp[c0]; o.us[1] = wp[c1]; o.us[2] = wp[c2]; o.us[3] = wp[c3];
            o.us[4] = wp[c4]; o.us[5] = wp[c5]; o.us[6] = wp[c6]; o.us[7] = wp[c7];
            *(ul2*)(AW3 + ((size_t)tloc * 3 + pi) * 112640 + (size_t)r * 352 + k0) = o.v2;
        }
    }
}

// ==================== GEMM bodies (64x64 wave tiles, dbuf, proven round-7 config) ====================

__device__ __forceinline__ void gm2_body(
    int bx, int tid, ushort* AsR,
    const ushort* __restrict__ Ws, const unsigned* __restrict__ s1bT,
    const int* __restrict__ idx2, float* __restrict__ drive, int t0)
{
    int tloc = bx / 24, rem = bx % 24;
    int mt = rem >> 2, nt4 = rem & 3;
    int t = t0 + tloc;
    int p = t & 1;
    int r0 = mt * 64, n0 = nt4 * 256;
    int ar = tid >> 2, ak8 = (tid & 3) * 8;
    int vR = idx2[t * 384 + r0 + ar];
    const ushort* Wrow = Ws + (size_t)p * 524288 + (size_t)(vR < 0 ? 0 : vR) * 512 + ak8;
    int wv = tid >> 6, lane = tid & 63;
    int mrow = lane & 31, kh8 = (lane >> 5) * 8;
    int nb = n0 + wv * 64 + mrow;
    f16v acc[2][2];
#pragma unroll
    for (int a = 0; a < 2; ++a)
#pragma unroll
        for (int b = 0; b < 2; ++b) acc[a][b] = (f16v)(0.f);

    ul2 c0r[3];
#pragma unroll
    for (int pi = 0; pi < 3; ++pi) c0r[pi] = *(const ul2*)(Wrow + (size_t)pi * 1048576);
#pragma unroll
    for (int pi = 0; pi < 3; ++pi) ldsWR(&AsR[ASOFF(0, pi, ar, ak8)], c0r[pi]);
    ul2 nxt[3];
#pragma unroll
    for (int pi = 0; pi < 3; ++pi) nxt[pi] = *(const ul2*)(Wrow + (size_t)pi * 1048576 + 32);
    unsigned w4c[2];
#pragma unroll
    for (int jj = 0; jj < 2; ++jj) w4c[jj] = s1bT[(size_t)t * 16 * 1024 + nb + jj * 32];
    __syncthreads();

    int cur = 0;
    for (int kc = 0; kc < 512; kc += 32) {
        if (kc + 32 < 512) {
#pragma unroll
            for (int pi = 0; pi < 3; ++pi) ldsWR(&AsR[ASOFF(cur ^ 1, pi, ar, ak8)], nxt[pi]);
        }
        unsigned w4n[2];
        if (kc + 32 < 512) {
#pragma unroll
            for (int jj = 0; jj < 2; ++jj)
                w4n[jj] = s1bT[((size_t)t * 16 + ((kc + 32) >> 5)) * 1024 + nb + jj * 32];
        }
        ul2 n2[3];
        if (kc + 64 < 512) {
#pragma unroll
            for (int pi = 0; pi < 3; ++pi)
                n2[pi] = *(const ul2*)(Wrow + (size_t)pi * 1048576 + kc + 64);
        }
#pragma unroll
        for (int s2 = 0; s2 < 2; ++s2) {
            int kcol = s2 * 16 + kh8;
            short8 bf[2];
#pragma unroll
            for (int jj = 0; jj < 2; ++jj) bf[jj] = expand8((w4c[jj] >> kcol) & 0xFFu);
#pragma unroll
            for (int wr2 = 0; wr2 < 2; ++wr2) {
                short8 af0 = ldsAF(&AsR[ASOFF(cur, 0, wr2 * 32 + mrow, kcol)]);
                short8 af1 = ldsAF(&AsR[ASOFF(cur, 1, wr2 * 32 + mrow, kcol)]);
                short8 af2 = ldsAF(&AsR[ASOFF(cur, 2, wr2 * 32 + mrow, kcol)]);
#pragma unroll
                for (int jj = 0; jj < 2; ++jj) {
                    acc[wr2][jj] = __builtin_amdgcn_mfma_f32_32x32x16_bf16(af2, bf[jj], acc[wr2][jj], 0, 0, 0);
                    acc[wr2][jj] = __builtin_amdgcn_mfma_f32_32x32x16_bf16(af1, bf[jj], acc[wr2][jj], 0, 0, 0);
                    acc[wr2][jj] = __builtin_amdgcn_mfma_f32_32x32x16_bf16(af0, bf[jj], acc[wr2][jj], 0, 0, 0);
                }
            }
        }
        __syncthreads();
        cur ^= 1;
        nxt[0] = n2[0]; nxt[1] = n2[1]; nxt[2] = n2[2];
        w4c[0] = w4n[0]; w4c[1] = w4n[1];
    }
#pragma unroll
    for (int wr2 = 0; wr2 < 2; ++wr2)
#pragma unroll
        for (int jj = 0; jj < 2; ++jj)
#pragma unroll
            for (int reg = 0; reg < 16; ++reg) {
                int rowl = r0 + wr2 * 32 + (reg & 3) + 8 * (reg >> 2) + 4 * (lane >> 5);
                drive[((size_t)tloc * 384 + rowl) * 1024 + nb + jj * 32] = acc[wr2][jj][reg];
            }
}

__device__ __forceinline__ void gm3_body(
    int bx, int tid, ushort* AsR,
    const ushort* __restrict__ AW3, const unsigned* __restrict__ s2bT,
    float* __restrict__ drive, int t0)
{
    int tloc = bx / 20, rem = bx % 20;
    int mt = rem >> 2, nt4 = rem & 3;
    int t = t0 + tloc;
    int r0 = mt * 64, n0 = nt4 * 256;
    int ar = tid >> 2, ak8 = (tid & 3) * 8;
    const ushort* Ab = AW3 + (size_t)tloc * 337920 + (size_t)(r0 + ar) * 352 + ak8;
    int wv = tid >> 6, lane = tid & 63;
    int mrow = lane & 31, kh8 = (lane >> 5) * 8;
    int nb = n0 + wv * 64 + mrow;
    f16v acc[2][2];
#pragma unroll
    for (int a = 0; a < 2; ++a)
#pragma unroll
        for (int b = 0; b < 2; ++b) acc[a][b] = (f16v)(0.f);

    ul2 c0r[3];
#pragma unroll
    for (int pi = 0; pi < 3; ++pi) c0r[pi] = *(const ul2*)(Ab + (size_t)pi * 112640);
#pragma unroll
    for (int pi = 0; pi < 3; ++pi) ldsWR(&AsR[ASOFF(0, pi, ar, ak8)], c0r[pi]);
    ul2 nxt[3];
#pragma unroll
    for (int pi = 0; pi < 3; ++pi) nxt[pi] = *(const ul2*)(Ab + (size_t)pi * 112640 + 32);
    unsigned w4c[2];
#pragma unroll
    for (int jj = 0; jj < 2; ++jj) w4c[jj] = s2bT[(size_t)t * 11 * 1024 + nb + jj * 32];
    __syncthreads();

    int cur = 0;
    for (int kc = 0; kc < 352; kc += 32) {
        if (kc + 32 < 352) {
#pragma unroll
            for (int pi = 0; pi < 3; ++pi) ldsWR(&AsR[ASOFF(cur ^ 1, pi, ar, ak8)], nxt[pi]);
        }
        unsigned w4n[2];
        if (kc + 32 < 352) {
#pragma unroll
            for (int jj = 0; jj < 2; ++jj)
                w4n[jj] = s2bT[((size_t)t * 11 + ((kc + 32) >> 5)) * 1024 + nb + jj * 32];
        }
        ul2 n2[3];
        if (kc + 64 < 352) {
#pragma unroll
            for (int pi = 0; pi < 3; ++pi)
                n2[pi] = *(const ul2*)(Ab + (size_t)pi * 112640 + kc + 64);
        }
#pragma unroll
        for (int s2 = 0; s2 < 2; ++s2) {
            int kcol = s2 * 16 + kh8;
            short8 bf[2];
#pragma unroll
            for (int jj = 0; jj < 2; ++jj) bf[jj] = expand8((w4c[jj] >> kcol) & 0xFFu);
#pragma unroll
            for (int wr2 = 0; wr2 < 2; ++wr2) {
                short8 af0 = ldsAF(&AsR[ASOFF(cur, 0, wr2 * 32 + mrow, kcol)]);
                short8 af1 = ldsAF(&AsR[ASOFF(cur, 1, wr2 * 32 + mrow, kcol)]);
                short8 af2 = ldsAF(&AsR[ASOFF(cur, 2, wr2 * 32 + mrow, kcol)]);
#pragma unroll
                for (int jj = 0; jj < 2; ++jj) {
                    acc[wr2][jj] = __builtin_amdgcn_mfma_f32_32x32x16_bf16(af2, bf[jj], acc[wr2][jj], 0, 0, 0);
                    acc[wr2][jj] = __builtin_amdgcn_mfma_f32_32x32x16_bf16(af1, bf[jj], acc[wr2][jj], 0, 0, 0);
                    acc[wr2][jj] = __builtin_amdgcn_mfma_f32_32x32x16_bf16(af0, bf[jj], acc[wr2][jj], 0, 0, 0);
                }
            }
        }
        __syncthreads();
        cur ^= 1;
        nxt[0] = n2[0]; nxt[1] = n2[1]; nxt[2] = n2[2];
        w4c[0] = w4n[0]; w4c[1] = w4n[1];
    }
#pragma unroll
    for (int wr2 = 0; wr2 < 2; ++wr2)
#pragma unroll
        for (int jj = 0; jj < 2; ++jj)
#pragma unroll
            for (int reg = 0; reg < 16; ++reg) {
                int rowl = r0 + wr2 * 32 + (reg & 3) + 8 * (reg >> 2) + 4 * (lane >> 5);
                drive[((size_t)tloc * 320 + rowl) * 1024 + nb + jj * 32] = acc[wr2][jj][reg];
            }
}

// standalone wrappers (prologue GM2 / epilogue GM3), XCD-swizzled
__global__ __launch_bounds__(256) void kGM2K(
    const ushort* __restrict__ Ws, const unsigned* __restrict__ s1bT,
    const int* __restrict__ idx2, float* __restrict__ drive, int t0)
{
    __shared__ ushort AsR[2 * 3 * 64 * 36];
    gm2_body(xcdSwz(blockIdx.x, gridDim.x), threadIdx.x, AsR, Ws, s1bT, idx2, drive, t0);
}
__global__ __launch_bounds__(256) void kGM3K(
    const ushort* __restrict__ AW3, const unsigned* __restrict__ s2bT,
    float* __restrict__ drive, int t0)
{
    __shared__ ushort AsR[2 * 3 * 64 * 36];
    gm3_body(xcdSwz(blockIdx.x, gridDim.x), threadIdx.x, AsR, AW3, s2bT, drive, t0);
}

// fused cross-chunk GEMM: work id swizzled so A-sharing siblings co-locate per XCD
__global__ __launch_bounds__(256) void kGMF(
    const ushort* __restrict__ W2S, const unsigned* __restrict__ s1bT,
    const int* __restrict__ idx2, float* __restrict__ drv2, int t0_2, int n2blocks,
    const ushort* __restrict__ AW3, const unsigned* __restrict__ s2bT,
    float* __restrict__ drv3, int t0_3)
{
    __shared__ ushort AsR[2 * 3 * 64 * 36];
    int w = xcdSwz(blockIdx.x, gridDim.x);
    if (w < n2blocks) gm2_body(w, threadIdx.x, AsR, W2S, s1bT, idx2, drv2, t0_2);
    else              gm3_body(w - n2blocks, threadIdx.x, AsR, AW3, s2bT, drv3, t0_3);
}

// ---- chunk recurrence body: one wave per (row, 64-col block), depth-2 drive prefetch ----
template<int MP, int KBP, bool BITS, int NACT>
__device__ __forceinline__ void rk_body(
    int bx, int tid,
    const float* __restrict__ drive, const float* __restrict__ bias,
    const int* __restrict__ list,
    float* __restrict__ mG, float* __restrict__ ssG,
    unsigned long long* __restrict__ bitsOut, int t0, int nt)
{
    int row = bx >> 2;                               // 0..1023
    int wv  = ((bx & 3) << 2) + (tid >> 6);          // nblk 0..15
    int lane = tid & 63;
    int n = (wv << 6) + lane;
    size_t idx = (size_t)row * 1024 + n;
    float mv = mG[idx];
    float cnt = 0.f;
    float bv = bias[row];
    const int* lp = list + row * NACT;               // wave-uniform -> scalar loads
    int t1 = t0 + nt;
    int s0 = 0;
    while (s0 < NACT && (lp[s0] >> 10) < t0) ++s0;
    int s1 = s0;
    while (s1 < NACT && (lp[s1] >> 10) < t1) ++s1;
    if (s0 < s1) {
        int v0 = lp[s0];
        float d0 = drive[((size_t)((v0 >> 10) - t0) * MP + (v0 & 1023)) * 1024 + n];
        int v1 = 0; float d1 = 0.f;
        if (s0 + 1 < s1) {
            v1 = lp[s0 + 1];
            d1 = drive[((size_t)((v1 >> 10) - t0) * MP + (v1 & 1023)) * 1024 + n];
        }
        for (int s = s0; s < s1; ++s) {
            int vc = v0;
            float dcur = d0;
            v0 = v1; d0 = d1;
            if (s + 2 < s1) {
                v1 = lp[s + 2];
                d1 = drive[((size_t)((v1 >> 10) - t0) * MP + (v1 & 1023)) * 1024 + n];
            }
            float d = dcur + bv;
            float m = mv * 0.5f + d;
            mv = m;
            bool sp = m > 0.5f;
            if (BITS) {
                unsigned long long bm = __ballot(sp);
                if (lane == 0) bitsOut[((size_t)(vc >> 10) * KBP + (vc & 1023)) * 16 + wv] = bm;
            }
            cnt += sp ? 1.f : 0.f;
        }
    }
    mG[idx] = mv;
    ssG[idx] += cnt;
}

template<int MP, int KBP, bool BITS, int NACT>
__global__ __launch_bounds__(256) void kRK(
    const float* __restrict__ drive, const float* __restrict__ bias,
    const int* __restrict__ list,
    float* __restrict__ mG, float* __restrict__ ssG,
    unsigned long long* __restrict__ bitsOut, int t0, int nt)
{
    rk_body<MP, KBP, BITS, NACT>(blockIdx.x, threadIdx.x, drive, bias, list,
                                 mG, ssG, bitsOut, t0, nt);
}

// fused cross-chunk recurrence: RK3(chunk c) [4096 blocks] + RK2(chunk c+1) [4096 blocks]
__global__ __launch_bounds__(256) void kRKF(
    const float* __restrict__ drv3, const float* __restrict__ b3,
    const int* __restrict__ list3, float* __restrict__ m3, float* __restrict__ ss3,
    int t0_3, int nt3,
    const float* __restrict__ drv2, const float* __restrict__ b2,
    const int* __restrict__ list2, float* __restrict__ m2, float* __restrict__ ss2,
    unsigned long long* __restrict__ s2bits, int t0_2, int nt2)
{
    int bx = blockIdx.x;
    if (bx < 4096)
        rk_body<320, 0, false, 25>(bx, threadIdx.x, drv3, b3, list3, m3, ss3,
                                   nullptr, t0_3, nt3);
    else
        rk_body<384, 352, true, 33>(bx - 4096, threadIdx.x, drv2, b2, list2, m2, ss2,
                                    s2bits, t0_2, nt2);
}

// ---- tail: ss transposes + fr; W4 GEMV partials into osum ----
__global__ __launch_bounds__(256) void kTail(
    const float* __restrict__ ssBase, const float* __restrict__ W4,
    float* __restrict__ osum, float* __restrict__ out, float* __restrict__ fr)
{
    int bx = blockIdx.x, tid = threadIdx.x;
    if (bx < 768) {
        __shared__ float Ls[64][65];
        __shared__ float red[4];
        int l = bx >> 8;
        int tile = bx & 255;
        int i0 = (tile >> 4) * 64, n0 = (tile & 15) * 64;
        const float* ss = ssBase + (size_t)l * MM;
        float* o = out + 10240 + (size_t)l * MM;
        float sum = 0.f;
#pragma unroll
        for (int j = 0; j < 16; ++j) {
            int flat = tid + 256 * j;
            int a = flat >> 6, c = flat & 63;
            float v = ss[(size_t)(i0 + a) * 1024 + n0 + c];
            Ls[a][c] = v;
            sum += v;
        }
        __syncthreads();
        for (int off = 32; off > 0; off >>= 1) sum += __shfl_down(sum, off, 64);
        if ((tid & 63) == 0) red[tid >> 6] = sum;
        __syncthreads();
        if (tid == 0) {
            float s = red[0] + red[1] + red[2] + red[3];
            atomicAdd(&fr[l], s * (1.0f / (1024.0f * 1024.0f * 98.0f)));
        }
#pragma unroll
        for (int j = 0; j < 16; ++j) {
            int flat = tid + 256 * j;
            int nn = flat >> 6, ii = flat & 63;
            o[(size_t)(n0 + nn) * 1024 + i0 + ii] = Ls[ii][nn] * (1.0f / 98.0f);
        }
    } else {
        int b = bx - 768;
        int ks = b >> 4, nt = b & 15;
        int n = nt * 64 + (tid & 63);
        int og = tid >> 6;
        const float* ss3 = ssBase + (size_t)2 * MM;
        float a0 = 0.f, a1 = 0.f, a2 = 0.f;
        int k0 = ks * 256;
        for (int k = k0; k < k0 + 256; ++k) {
            float v = ss3[(size_t)k * 1024 + n];
            a0 += v * W4[og * 1024 + k];
            a1 += v * W4[(og + 4) * 1024 + k];
            if (og < 2) a2 += v * W4[(og + 8) * 1024 + k];
        }
        atomicAdd(&osum[n * OUTD + og], a0);
        atomicAdd(&osum[n * OUTD + og + 4], a1);
        if (og < 2) atomicAdd(&osum[n * OUTD + og + 8], a2);
    }
}

__global__ void kOut(const float* __restrict__ osum, const float* __restrict__ b4,
                     float* __restrict__ out)
{
    int idx = blockIdx.x * 256 + threadIdx.x;
    if (idx < 1024 * OUTD) out[idx] = osum[idx] * (1.0f / 98.0f) + b4[idx % OUTD];
}

extern "C" void kernel_launch(void* const* d_in, const int* in_sizes, int n_in,
                              void* d_out, int out_size, void* d_ws, size_t ws_size,
                              hipStream_t stream)
{
    const float* input = (const float*)d_in[0];
    const float* W1    = (const float*)d_in[1];
    const float* b1    = (const float*)d_in[2];
    const float* W2    = (const float*)d_in[3];
    const float* b2    = (const float*)d_in[4];
    const float* W3    = (const float*)d_in[5];
    const float* b3    = (const float*)d_in[6];
    const float* W4    = (const float*)d_in[7];
    const float* b4    = (const float*)d_in[8];

    float* ws = (float*)d_ws;
    float* ss1  = ws;
    float* ss2  = ws + MM;
    float* ss3  = ws + 2 * MM;
    float* m2   = ws + 3 * MM;
    float* m3   = ws + 4 * MM;
    float* osum = ws + OFF_OSUM;
    float* xT   = ws + OFF_XT;
    int*   tabs = (int*)(ws + OFF_XT);   // reuses xT region after kL1
    int* idx2  = tabs + TAB_IDX2;
    int* idx3  = tabs + TAB_IDX3;
    int* cq3   = tabs + TAB_CQ3;
    int* list2 = tabs + TAB_L2;
    int* list3 = tabs + TAB_L3;
    unsigned int* s1b  = (unsigned int*)(ws + OFF_S1B);
    unsigned int* s2b  = (unsigned int*)(ws + OFF_S2B);
    unsigned int* s1bT = (unsigned int*)(ws + OFF_S1BT);
    unsigned int* s2bT = (unsigned int*)(ws + OFF_S2BT);
    ushort* W2S = (ushort*)(ws + OFF_W2S);
    ushort* W3S = (ushort*)(ws + OFF_W3S);
    float* out  = (float*)d_out;

    // pick the largest t-chunk the workspace can hold.
    size_t availF = ws_size / sizeof(float);
    constexpr size_t PER_T = AW3_PER_T + 384 * 1024 + 320 * 1024;   // 889,856 floats
    int tc = 10;   // guaranteed-fit fallback (~94 MB)
    const int cands[8] = {98, 66, 49, 40, 33, 25, 14, 10};
    for (int ci = 0; ci < 8; ++ci) {
        if (FIX_END + (size_t)cands[ci] * PER_T <= availF) { tc = cands[ci]; break; }
    }
    ushort* AW3 = (ushort*)(ws + FIX_END);
    float* drv2 = ws + FIX_END + (size_t)tc * AW3_PER_T;
    float* drv3 = drv2 + (size_t)tc * 384 * 1024;

    hipMemsetAsync(ws, 0, (5 * MM + 10240) * sizeof(float), stream);   // ss, m2, m3, osum
    hipMemsetAsync(s2b, 0, 1103872 * sizeof(unsigned int), stream);    // layer-2 bits (pad ranks)
    hipMemsetAsync(out + 3155968, 0, 3 * sizeof(float), stream);       // fr

    kSplit<<<8224, 256, 0, stream>>>(W2, W3, W2S, W3S);
    kPrep<<<208, 256, 0, stream>>>(input, xT);
    kL1<<<1024, 256, 0, stream>>>(xT, W1, b1, (unsigned long long*)s1b, ss1);
    kTab2<<<98, 256, 0, stream>>>(idx2, idx3, cq3);                    // after kL1: reuses xT mem
    kListCF<3, 33><<<132, 256, 0, stream>>>(list2);
    kListCF<4, 25><<<100, 256, 0, stream>>>(list3);
    kXb<512><<<1568, 256, 0, stream>>>(s1b, s1bT, 0);

    int nc = (TTL + tc - 1) / tc;
    auto ntOf = [&](int c) { int t0c = c * tc; return (TTL - t0c < tc) ? (TTL - t0c) : tc; };

    // software pipeline with cross-chunk fusion:
    //   GM2(0), RK2(0), X(0), { GMF[GM2(c+1)+GM3(c)], RKF[RK3(c)+RK2(c+1)], X(c+1) }, GM3(last), RK3(last)
    kGM2K<<<ntOf(0) * 24, 256, 0, stream>>>(W2S, s1bT, idx2, drv2, 0);
    kRK<384, 352, true, 33><<<4096, 256, 0, stream>>>(drv2, b2, list2, m2, ss2,
                                                      (unsigned long long*)s2b, 0, ntOf(0));
    kXbG3A<<<ntOf(0) * 66, 256, 0, stream>>>(s2b, s2bT, W3S, idx3, cq3, AW3, 0);

    for (int c = 0; c + 1 < nc; ++c) {
        int t03 = c * tc, t02 = (c + 1) * tc;
        int n2b = ntOf(c + 1) * 24, n3b = ntOf(c) * 20;
        kGMF<<<n2b + n3b, 256, 0, stream>>>(W2S, s1bT, idx2, drv2, t02, n2b,
                                            AW3, s2bT, drv3, t03);
        kRKF<<<8192, 256, 0, stream>>>(drv3, b3, list3, m3, ss3, t03, ntOf(c),
                                       drv2, b2, list2, m2, ss2,
                                       (unsigned long long*)s2b, t02, ntOf(c + 1));
        kXbG3A<<<ntOf(c + 1) * 66, 256, 0, stream>>>(s2b, s2bT, W3S, idx3, cq3, AW3, t02);
    }
    int cl = nc - 1, t0l = cl * tc;
    kGM3K<<<ntOf(cl) * 20, 256, 0, stream>>>(AW3, s2bT, drv3, t0l);
    kRK<320, 0, false, 25><<<4096, 256, 0, stream>>>(drv3, b3, list3, m3, ss3,
                                                     nullptr, t0l, ntOf(cl));

    kTail<<<832, 256, 0, stream>>>(ss1, W4, osum, out, out + 3155968);
    kOut<<<40, 256, 0, stream>>>(osum, b4, out);
}